// Round 1
// baseline (1616.860 us; speedup 1.0000x reference)
//
#include <hip/hip_runtime.h>
#include <math.h>

#define HD 128
#define GG 64

__device__ __forceinline__ float leaky(float x, float s) { return x > 0.f ? x : s * x; }

// ---------------- zero fill ----------------
__global__ void k_zero_f32(float* p, int n) {
    int i = blockIdx.x * blockDim.x + threadIdx.x;
    if (i < n) p[i] = 0.f;
}
__global__ void k_zero_i32(int* p, int n) {
    int i = blockIdx.x * blockDim.x + threadIdx.x;
    if (i < n) p[i] = 0;
}

// ---------------- GEMM: C[n,128] = A[n,128] @ W[128,128] ----------------
// BM=64 rows/block, 256 threads, thread tile 8 rows x 4 cols.
// LDS: A-tile 32KB + W-half 32KB = 64KB -> 2 blocks/CU.
__global__ __launch_bounds__(256) void k_gemm(const float* __restrict__ A,
                                              const float* __restrict__ W,
                                              float* __restrict__ C, int n) {
    __shared__ float As[64 * HD];
    __shared__ float Bs[64 * HD];
    const int tid = threadIdx.x;
    const int base = blockIdx.x * 64;
    const float4* A4 = (const float4*)A;
    const float4* W4 = (const float4*)W;
    float4* As4 = (float4*)As;
    float4* Bs4 = (float4*)Bs;

    // load A tile (64 rows x 32 float4), guarded
#pragma unroll
    for (int j = 0; j < 8; ++j) {
        int flat = tid + j * 256;           // 0..2047
        int r = flat >> 5, k4 = flat & 31;
        float4 v = make_float4(0.f, 0.f, 0.f, 0.f);
        if (base + r < n) v = A4[(size_t)(base + r) * 32 + k4];
        As4[flat] = v;
    }
    // load W rows 0..63
#pragma unroll
    for (int j = 0; j < 8; ++j) {
        int flat = tid + j * 256;
        Bs4[flat] = W4[flat];
    }
    __syncthreads();

    const int tx = tid & 31;   // col group: cols tx*4 .. tx*4+3
    const int ty = tid >> 5;   // row group: rows ty*8 .. ty*8+7
    float acc[8][4];
#pragma unroll
    for (int i = 0; i < 8; ++i)
#pragma unroll
        for (int c = 0; c < 4; ++c) acc[i][c] = 0.f;

    auto compute = [&](int koff) {
#pragma unroll 4
        for (int k = 0; k < 64; k += 4) {
            float4 b0 = Bs4[(k + 0) * 32 + tx];
            float4 b1 = Bs4[(k + 1) * 32 + tx];
            float4 b2 = Bs4[(k + 2) * 32 + tx];
            float4 b3 = Bs4[(k + 3) * 32 + tx];
#pragma unroll
            for (int i = 0; i < 8; ++i) {
                float4 a = As4[(ty * 8 + i) * 32 + ((koff + k) >> 2)];
                acc[i][0] = fmaf(a.x, b0.x, acc[i][0]);
                acc[i][0] = fmaf(a.y, b1.x, acc[i][0]);
                acc[i][0] = fmaf(a.z, b2.x, acc[i][0]);
                acc[i][0] = fmaf(a.w, b3.x, acc[i][0]);
                acc[i][1] = fmaf(a.x, b0.y, acc[i][1]);
                acc[i][1] = fmaf(a.y, b1.y, acc[i][1]);
                acc[i][1] = fmaf(a.z, b2.y, acc[i][1]);
                acc[i][1] = fmaf(a.w, b3.y, acc[i][1]);
                acc[i][2] = fmaf(a.x, b0.z, acc[i][2]);
                acc[i][2] = fmaf(a.y, b1.z, acc[i][2]);
                acc[i][2] = fmaf(a.z, b2.z, acc[i][2]);
                acc[i][2] = fmaf(a.w, b3.z, acc[i][2]);
                acc[i][3] = fmaf(a.x, b0.w, acc[i][3]);
                acc[i][3] = fmaf(a.y, b1.w, acc[i][3]);
                acc[i][3] = fmaf(a.z, b2.w, acc[i][3]);
                acc[i][3] = fmaf(a.w, b3.w, acc[i][3]);
            }
        }
    };

    compute(0);
    __syncthreads();
    // load W rows 64..127
#pragma unroll
    for (int j = 0; j < 8; ++j) {
        int flat = tid + j * 256;
        Bs4[flat] = W4[2048 + flat];
    }
    __syncthreads();
    compute(64);

    float4* C4 = (float4*)C;
#pragma unroll
    for (int i = 0; i < 8; ++i) {
        int r = base + ty * 8 + i;
        if (r < n) {
            float4 o = make_float4(acc[i][0], acc[i][1], acc[i][2], acc[i][3]);
            C4[(size_t)r * 32 + tx] = o;
        }
    }
}

// ---------------- a_s, a_d: per-row dots with attention vectors ----------------
__global__ __launch_bounds__(256) void k_asad(const float* __restrict__ hW,
                                              const float* __restrict__ att_s,
                                              const float* __restrict__ att_d,
                                              float* __restrict__ a_s,
                                              float* __restrict__ a_d, int n) {
    int row = blockIdx.x * 4 + (threadIdx.x >> 6);
    int lane = threadIdx.x & 63;
    if (row >= n) return;
    float2 v = ((const float2*)hW)[(size_t)row * 64 + lane];
    float2 s2 = ((const float2*)att_s)[lane];
    float2 d2 = ((const float2*)att_d)[lane];
    float vs = v.x * s2.x + v.y * s2.y;
    float vd = v.x * d2.x + v.y * d2.y;
#pragma unroll
    for (int off = 32; off; off >>= 1) {
        vs += __shfl_xor(vs, off, 64);
        vd += __shfl_xor(vd, off, 64);
    }
    if (lane == 0) { a_s[row] = vs; a_d[row] = vd; }
}

// ---------------- CSR build ----------------
__global__ void k_count(const int* __restrict__ dst, int* __restrict__ counts, int e) {
    int i = blockIdx.x * blockDim.x + threadIdx.x;
    if (i < e) atomicAdd(&counts[dst[i]], 1);
}

__global__ void k_scan_reduce(const int* __restrict__ counts, int* __restrict__ bsums, int n) {
    __shared__ int s[256];
    int tid = threadIdx.x;
    int i = blockIdx.x * 256 + tid;
    s[tid] = (i < n) ? counts[i] : 0;
    __syncthreads();
#pragma unroll
    for (int off = 128; off; off >>= 1) {
        if (tid < off) s[tid] += s[tid + off];
        __syncthreads();
    }
    if (tid == 0) bsums[blockIdx.x] = s[0];
}

__global__ void k_scan_top(const int* __restrict__ bsums, int* __restrict__ boffs,
                           int nb, int* __restrict__ offs, int n_nodes) {
    __shared__ int s[512];
    int tid = threadIdx.x;
    int own = (tid < nb) ? bsums[tid] : 0;
    s[tid] = own;
    __syncthreads();
    for (int off = 1; off < 512; off <<= 1) {
        int t = 0;
        if (tid >= off) t = s[tid - off];
        __syncthreads();
        s[tid] += t;
        __syncthreads();
    }
    if (tid < nb) boffs[tid] = s[tid] - own;       // exclusive block offset
    if (tid == 511) offs[n_nodes] = s[511];        // total = E
}

__global__ void k_scan_apply(const int* __restrict__ counts, const int* __restrict__ boffs,
                             int* __restrict__ offs, int n) {
    __shared__ int s[256];
    int tid = threadIdx.x;
    int i = blockIdx.x * 256 + tid;
    int own = (i < n) ? counts[i] : 0;
    s[tid] = own;
    __syncthreads();
    for (int off = 1; off < 256; off <<= 1) {
        int t = 0;
        if (tid >= off) t = s[tid - off];
        __syncthreads();
        s[tid] += t;
        __syncthreads();
    }
    if (i < n) offs[i] = boffs[blockIdx.x] + s[tid] - own;  // exclusive
}

__global__ void k_scatter(const int* __restrict__ src, const int* __restrict__ dst,
                          const int* __restrict__ offs, int* __restrict__ cursor,
                          int* __restrict__ esrc, int e) {
    int i = blockIdx.x * blockDim.x + threadIdx.x;
    if (i < e) {
        int d = dst[i];
        int pos = offs[d] + atomicAdd(&cursor[d], 1);
        esrc[pos] = src[i];
    }
}

// ---------------- fused attention softmax + aggregation ----------------
// h[d] = (sum_e ex_e * hW[src_e]) / (sum_e ex_e + 1e-16) + bias
// One 32-lane group per dst node; lane holds float4 of features.
__global__ __launch_bounds__(256) void k_agg(const float* __restrict__ hW,
                                             const int* __restrict__ offs,
                                             const int* __restrict__ esrc,
                                             const float* __restrict__ a_s,
                                             const float* __restrict__ a_d,
                                             const float* __restrict__ bias,
                                             float* __restrict__ hout, int n) {
    int d = blockIdx.x * 8 + (threadIdx.x >> 5);
    int lane = threadIdx.x & 31;
    if (d >= n) return;
    int p0 = offs[d], p1 = offs[d + 1];
    float ad = a_d[d];
    const float4* hW4 = (const float4*)hW;
    float4 acc = make_float4(0.f, 0.f, 0.f, 0.f);
    float ssum = 0.f;
    for (int p = p0; p < p1; ++p) {
        int s = esrc[p];
        float e = a_s[s] + ad;
        e = leaky(e, 0.2f);
        float ex = __expf(e);
        ssum += ex;
        float4 hv = hW4[(size_t)s * 32 + lane];
        acc.x = fmaf(ex, hv.x, acc.x);
        acc.y = fmaf(ex, hv.y, acc.y);
        acc.z = fmaf(ex, hv.z, acc.z);
        acc.w = fmaf(ex, hv.w, acc.w);
    }
    float inv = 1.f / (ssum + 1e-16f);
    float4 b4 = ((const float4*)bias)[lane];
    float4 o = make_float4(acc.x * inv + b4.x, acc.y * inv + b4.y,
                           acc.z * inv + b4.z, acc.w * inv + b4.w);
    ((float4*)hout)[(size_t)d * 32 + lane] = o;
}

// ---------------- GraphNorm: column stats ----------------
__global__ __launch_bounds__(256) void k_colstat(const float* __restrict__ h,
                                                 float* __restrict__ colsum,
                                                 float* __restrict__ colsq, int n) {
    int c = threadIdx.x & 127;
    int half = threadIdx.x >> 7;
    int rows_per = (n + gridDim.x - 1) / gridDim.x;
    int r0 = blockIdx.x * rows_per;
    int r1 = min(r0 + rows_per, n);
    float s = 0.f, q = 0.f;
    for (int r = r0 + half; r < r1; r += 2) {
        float v = h[(size_t)r * HD + c];
        s += v;
        q = fmaf(v, v, q);
    }
    atomicAdd(&colsum[c], s);
    atomicAdd(&colsq[c], q);
}

// per-column affine: alpha = w * rsqrt(var+eps); beta = b - mean*scale*alpha
__global__ void k_coeff(const float* __restrict__ colsum, const float* __restrict__ colsq,
                        const float* __restrict__ w, const float* __restrict__ b,
                        const float* __restrict__ ms, float* __restrict__ alpha,
                        float* __restrict__ beta, float inv_n) {
    int c = threadIdx.x;
    float mean = colsum[c] * inv_n;
    float ex2 = colsq[c] * inv_n;
    float m2 = mean * ms[c];
    float var = ex2 - 2.f * m2 * mean + m2 * m2;
    float a = w[c] * rsqrtf(var + 1e-5f);
    alpha[c] = a;
    beta[c] = b[c] - m2 * a;
}

__global__ void k_apply(float* __restrict__ h, const float* __restrict__ alpha,
                        const float* __restrict__ beta, int n) {
    int i = blockIdx.x * blockDim.x + threadIdx.x;  // over n*32 float4
    if (i >= n * 32) return;
    int cb = (i & 31) << 2;
    float4 v = ((float4*)h)[i];
    float4 al = *(const float4*)&alpha[cb];
    float4 be = *(const float4*)&beta[cb];
    v.x = leaky(fmaf(v.x, al.x, be.x), 0.01f);
    v.y = leaky(fmaf(v.y, al.y, be.y), 0.01f);
    v.z = leaky(fmaf(v.z, al.z, be.z), 0.01f);
    v.w = leaky(fmaf(v.w, al.w, be.w), 0.01f);
    ((float4*)h)[i] = v;
}

// ---------------- global_add_pool (batch sorted -> run accumulation) ----------------
__global__ __launch_bounds__(256) void k_pool(const float* __restrict__ h,
                                              const int* __restrict__ batch,
                                              float* __restrict__ pooled, int n) {
    int c = threadIdx.x & 127;
    int half = threadIdx.x >> 7;
    int base = blockIdx.x * 64 + half * 32;
    float acc = 0.f;
    int cur = -1;
    for (int j = 0; j < 32; ++j) {
        int r = base + j;
        if (r >= n) break;
        int g = batch[r];
        if (g != cur) {
            if (cur >= 0) atomicAdd(&pooled[cur * HD + c], acc);
            acc = 0.f;
            cur = g;
        }
        acc += h[(size_t)r * HD + c];
    }
    if (cur >= 0) atomicAdd(&pooled[cur * HD + c], acc);
}

// ---------------- final MLP: out = leaky(pooled@W1+b1, .01) @ W2 + b2 ----------------
__global__ __launch_bounds__(128) void k_mlp(const float* __restrict__ pooled,
                                             const float* __restrict__ W1,
                                             const float* __restrict__ b1,
                                             const float* __restrict__ W2,
                                             const float* __restrict__ b2,
                                             float* __restrict__ out) {
    __shared__ float pr[HD];
    __shared__ float zs[HD];
    int g = blockIdx.x, t = threadIdx.x;
    pr[t] = pooled[g * HD + t];
    __syncthreads();
    float acc = b1[t];
#pragma unroll 8
    for (int k = 0; k < HD; ++k) acc = fmaf(pr[k], W1[k * HD + t], acc);
    zs[t] = leaky(acc, 0.01f);
    __syncthreads();
    if (t < 64) {
        float a2 = b2[t];
#pragma unroll 8
        for (int k = 0; k < HD; ++k) a2 = fmaf(zs[k], W2[k * 64 + t], a2);
        out[g * 64 + t] = a2;
    }
}

extern "C" void kernel_launch(void* const* d_in, const int* in_sizes, int n_in,
                              void* d_out, int out_size, void* d_ws, size_t ws_size,
                              hipStream_t stream) {
    const float* x        = (const float*)d_in[0];
    const int*   ei       = (const int*)d_in[1];
    const int*   batch    = (const int*)d_in[2];
    const float* Ws       = (const float*)d_in[3];
    const float* att_src  = (const float*)d_in[4];
    const float* att_dst  = (const float*)d_in[5];
    const float* conv_bias= (const float*)d_in[6];
    const float* gn_w     = (const float*)d_in[7];
    const float* gn_b     = (const float*)d_in[8];
    const float* gn_ms    = (const float*)d_in[9];
    const float* W1       = (const float*)d_in[10];
    const float* b1       = (const float*)d_in[11];
    const float* W2       = (const float*)d_in[12];
    const float* b2       = (const float*)d_in[13];
    float* out = (float*)d_out;

    const int n = in_sizes[2];       // 100000
    const int e = in_sizes[1] / 2;   // 600000
    const int* src = ei;
    const int* dst = ei + e;

    float* ws     = (float*)d_ws;
    float* hW     = ws;                              // n*HD
    float* h      = hW + (size_t)n * HD;             // n*HD
    float* a_s    = h + (size_t)n * HD;              // n
    float* a_d    = a_s + n;                         // n
    float* colsum = a_d + n;                         // HD
    float* colsq  = colsum + HD;                     // HD
    float* alpha  = colsq + HD;                      // HD
    float* beta   = alpha + HD;                      // HD
    float* pooled = beta + HD;                       // GG*HD
    int* counts   = (int*)(pooled + GG * HD);        // n
    int* cursor   = counts + n;                      // n
    int* offs     = cursor + n;                      // n+1
    int* esrc     = offs + n + 1;                    // e
    int* bsums    = esrc + e;                        // 512
    int* boffs    = bsums + 512;                     // 512

    const int nb = (n + 255) / 256;

    // ---- CSR build (dst-sorted adjacency), reused by all 3 layers ----
    k_zero_i32<<<(2 * n + 255) / 256, 256, 0, stream>>>(counts, 2 * n); // counts + cursor
    k_count<<<(e + 255) / 256, 256, 0, stream>>>(dst, counts, e);
    k_scan_reduce<<<nb, 256, 0, stream>>>(counts, bsums, n);
    k_scan_top<<<1, 512, 0, stream>>>(bsums, boffs, nb, offs, n);
    k_scan_apply<<<nb, 256, 0, stream>>>(counts, boffs, offs, n);
    k_scatter<<<(e + 255) / 256, 256, 0, stream>>>(src, dst, offs, cursor, esrc, e);

    // ---- GAT layers ----
    const float* hin = x;
    for (int l = 0; l < 3; ++l) {
        k_gemm<<<(n + 63) / 64, 256, 0, stream>>>(hin, Ws + l * HD * HD, hW, n);
        k_asad<<<(n + 3) / 4, 256, 0, stream>>>(hW, att_src + l * HD, att_dst + l * HD,
                                                a_s, a_d, n);
        k_agg<<<(n + 7) / 8, 256, 0, stream>>>(hW, offs, esrc, a_s, a_d,
                                               conv_bias + l * HD, h, n);
        if (l < 2) {
            k_zero_f32<<<1, 256, 0, stream>>>(colsum, 2 * HD);  // colsum + colsq
            k_colstat<<<400, 256, 0, stream>>>(h, colsum, colsq, n);
            k_coeff<<<1, HD, 0, stream>>>(colsum, colsq, gn_w + l * HD, gn_b + l * HD,
                                          gn_ms + l * HD, alpha, beta, 1.0f / n);
            k_apply<<<(n * 32 + 255) / 256, 256, 0, stream>>>(h, alpha, beta, n);
        }
        hin = h;
    }

    // ---- pool + MLP ----
    k_zero_f32<<<(GG * HD + 255) / 256, 256, 0, stream>>>(pooled, GG * HD);
    k_pool<<<(n + 63) / 64, 256, 0, stream>>>(h, batch, pooled, n);
    k_mlp<<<GG, HD, 0, stream>>>(pooled, W1, b1, W2, b2, out);
}

// Round 2
// 532.440 us; speedup vs baseline: 3.0367x; 3.0367x over previous
//
#include <hip/hip_runtime.h>
#include <math.h>

#define HD 128
#define GG 64

typedef __attribute__((ext_vector_type(8))) short short8;
typedef __attribute__((ext_vector_type(4))) float f32x4;

__device__ __forceinline__ float leaky(float x, float s) { return x > 0.f ? x : s * x; }

__device__ __forceinline__ unsigned short bf16_of(float f) {
    union { float f; unsigned u; } v; v.f = f;
    unsigned r = v.u + 0x7fffu + ((v.u >> 16) & 1u);
    return (unsigned short)(r >> 16);
}
__device__ __forceinline__ float f_of_bf16(unsigned short u) {
    union { unsigned u; float f; } v; v.u = ((unsigned)u) << 16;
    return v.f;
}

// ---------------- zero fill ----------------
__global__ void k_zero_f32(float* p, int n) {
    int i = blockIdx.x * blockDim.x + threadIdx.x;
    if (i < n) p[i] = 0.f;
}
__global__ void k_zero_i32(int* p, int n) {
    int i = blockIdx.x * blockDim.x + threadIdx.x;
    if (i < n) p[i] = 0;
}

// ---------------- W -> Wt bf16 (transposed: Wt[l][n][k] = W[l][k][n]) ----------------
__global__ void k_convW(const float* __restrict__ Ws, unsigned short* __restrict__ Wt) {
    int i = blockIdx.x * 256 + threadIdx.x;
    if (i >= 3 * 16384) return;
    int l = i >> 14, rem = i & 16383;
    int nn = rem >> 7, k = rem & 127;
    Wt[i] = bf16_of(Ws[l * 16384 + k * 128 + nn]);
}

// ---------------- MFMA GEMM: hWb[n,128](bf16) = norm(A)[n,128] @ W ----------------
// Fused: optional GraphNorm affine+leaky on A load; a_s/a_d row-dot epilogue.
// Block: 128 rows, 256 threads (4 waves). Wave w: rows w*32..w*32+31, all 128 cols.
// LDS: A-tile 32KB bf16 + Wt 32KB bf16 = 64KB -> 2 blocks/CU. Memory-bound
// (98KB global traffic/block >> LDS/MFMA cycles), so no LDS padding needed.
__global__ __launch_bounds__(256) void k_gemm_mfma(
    const float* __restrict__ A, const unsigned short* __restrict__ Wt,
    const float* __restrict__ att_s, const float* __restrict__ att_d,
    const float* __restrict__ alpha, const float* __restrict__ beta, int use_norm,
    unsigned short* __restrict__ hWb, float* __restrict__ a_s, float* __restrict__ a_d,
    int n) {
    __shared__ unsigned short As[128 * 128];
    __shared__ unsigned short Bs[128 * 128];
    const int tid = threadIdx.x;
    const int base = blockIdx.x * 128;

    // stage Wt (bf16, already transposed): 32KB, 8 x uint4 per thread
    const uint4* Wt4 = (const uint4*)Wt;
    uint4* Bs4 = (uint4*)Bs;
#pragma unroll
    for (int j = 0; j < 8; ++j) Bs4[tid + j * 256] = Wt4[tid + j * 256];

    // stage A: load fp32, optional affine+leaky, convert bf16
    const float4* A4 = (const float4*)A;
#pragma unroll
    for (int j = 0; j < 16; ++j) {
        int flat = tid + j * 256;           // 0..4095 float4 slots
        int r = flat >> 5, c4 = flat & 31;
        float4 v = make_float4(0.f, 0.f, 0.f, 0.f);
        if (base + r < n) v = A4[(size_t)(base + r) * 32 + c4];
        if (use_norm) {
            float4 al = ((const float4*)alpha)[c4];
            float4 be = ((const float4*)beta)[c4];
            v.x = leaky(fmaf(v.x, al.x, be.x), 0.01f);
            v.y = leaky(fmaf(v.y, al.y, be.y), 0.01f);
            v.z = leaky(fmaf(v.z, al.z, be.z), 0.01f);
            v.w = leaky(fmaf(v.w, al.w, be.w), 0.01f);
        }
        ushort4 b;
        b.x = bf16_of(v.x); b.y = bf16_of(v.y); b.z = bf16_of(v.z); b.w = bf16_of(v.w);
        *(ushort4*)&As[r * 128 + c4 * 4] = b;
    }
    __syncthreads();

    const int wave = tid >> 6;
    const int lane = tid & 63;
    const int m16 = lane & 15;
    const int quad = lane >> 4;

    f32x4 acc[2][8];
#pragma unroll
    for (int rt = 0; rt < 2; ++rt)
#pragma unroll
        for (int ct = 0; ct < 8; ++ct) acc[rt][ct] = (f32x4){0.f, 0.f, 0.f, 0.f};

#pragma unroll
    for (int kk = 0; kk < 4; ++kk) {      // K in steps of 32
        short8 af[2];
#pragma unroll
        for (int rt = 0; rt < 2; ++rt) {
            int row = wave * 32 + rt * 16 + m16;
            af[rt] = *(const short8*)&As[row * 128 + kk * 32 + quad * 8];
        }
#pragma unroll
        for (int ct = 0; ct < 8; ++ct) {
            int col = ct * 16 + m16;
            short8 bfr = *(const short8*)&Bs[col * 128 + kk * 32 + quad * 8];
            acc[0][ct] = __builtin_amdgcn_mfma_f32_16x16x32_bf16(af[0], bfr, acc[0][ct], 0, 0, 0);
            acc[1][ct] = __builtin_amdgcn_mfma_f32_16x16x32_bf16(af[1], bfr, acc[1][ct], 0, 0, 0);
        }
    }
    __syncthreads();   // As fully consumed; reuse as hW staging

    // epilogue: stash bf16 hW into As; fused a_s/a_d row dots from fp32 acc
#pragma unroll
    for (int rt = 0; rt < 2; ++rt) {
#pragma unroll
        for (int reg = 0; reg < 4; ++reg) {
            int lrow = wave * 32 + rt * 16 + quad * 4 + reg;
            float s = 0.f, dd = 0.f;
#pragma unroll
            for (int ct = 0; ct < 8; ++ct) {
                float v = acc[rt][ct][reg];
                int col = ct * 16 + m16;
                As[lrow * 128 + col] = bf16_of(v);
                s = fmaf(v, att_s[col], s);
                dd = fmaf(v, att_d[col], dd);
            }
#pragma unroll
            for (int off = 1; off < 16; off <<= 1) {
                s += __shfl_xor(s, off, 64);
                dd += __shfl_xor(dd, off, 64);
            }
            if (m16 == 0) {
                int gr = base + lrow;
                if (gr < n) { a_s[gr] = s; a_d[gr] = dd; }
            }
        }
    }
    __syncthreads();

    // coalesced bf16 store of the tile
    uint4* out4 = (uint4*)hWb;
    const uint4* AsC = (const uint4*)As;
#pragma unroll
    for (int j = 0; j < 8; ++j) {
        int flat = tid + j * 256;           // 2048 uint4 in tile
        int r = flat >> 4;
        if (base + r < n) out4[(size_t)base * 16 + flat] = AsC[flat];
    }
}

// ---------------- CSR build ----------------
__global__ void k_count(const int* __restrict__ dst, int* __restrict__ counts, int e) {
    int i = blockIdx.x * blockDim.x + threadIdx.x;
    if (i < e) atomicAdd(&counts[dst[i]], 1);
}

__global__ void k_scan_reduce(const int* __restrict__ counts, int* __restrict__ bsums, int n) {
    __shared__ int s[256];
    int tid = threadIdx.x;
    int i = blockIdx.x * 256 + tid;
    s[tid] = (i < n) ? counts[i] : 0;
    __syncthreads();
#pragma unroll
    for (int off = 128; off; off >>= 1) {
        if (tid < off) s[tid] += s[tid + off];
        __syncthreads();
    }
    if (tid == 0) bsums[blockIdx.x] = s[0];
}

__global__ void k_scan_top(const int* __restrict__ bsums, int* __restrict__ boffs,
                           int nb, int* __restrict__ offs, int n_nodes) {
    __shared__ int s[512];
    int tid = threadIdx.x;
    int own = (tid < nb) ? bsums[tid] : 0;
    s[tid] = own;
    __syncthreads();
    for (int off = 1; off < 512; off <<= 1) {
        int t = 0;
        if (tid >= off) t = s[tid - off];
        __syncthreads();
        s[tid] += t;
        __syncthreads();
    }
    if (tid < nb) boffs[tid] = s[tid] - own;
    if (tid == 511) offs[n_nodes] = s[511];
}

__global__ void k_scan_apply(const int* __restrict__ counts, const int* __restrict__ boffs,
                             int* __restrict__ offs, int n) {
    __shared__ int s[256];
    int tid = threadIdx.x;
    int i = blockIdx.x * 256 + tid;
    int own = (i < n) ? counts[i] : 0;
    s[tid] = own;
    __syncthreads();
    for (int off = 1; off < 256; off <<= 1) {
        int t = 0;
        if (tid >= off) t = s[tid - off];
        __syncthreads();
        s[tid] += t;
        __syncthreads();
    }
    if (i < n) offs[i] = boffs[blockIdx.x] + s[tid] - own;
}

__global__ void k_scatter(const int* __restrict__ src, const int* __restrict__ dst,
                          const int* __restrict__ offs, int* __restrict__ cursor,
                          int* __restrict__ esrc, int e) {
    int i = blockIdx.x * blockDim.x + threadIdx.x;
    if (i < e) {
        int d = dst[i];
        int pos = offs[d] + atomicAdd(&cursor[d], 1);
        esrc[pos] = src[i];
    }
}

// ---------------- fused attention softmax + aggregation (bf16 hW gather) ----------------
__global__ __launch_bounds__(256) void k_agg(const unsigned short* __restrict__ hWb,
                                             const int* __restrict__ offs,
                                             const int* __restrict__ esrc,
                                             const float* __restrict__ a_s,
                                             const float* __restrict__ a_d,
                                             const float* __restrict__ bias,
                                             float* __restrict__ hout, int n) {
    int d = blockIdx.x * 8 + (threadIdx.x >> 5);
    int lane = threadIdx.x & 31;
    if (d >= n) return;
    int p0 = offs[d], p1 = offs[d + 1];
    float ad = a_d[d];
    const ushort4* hW4 = (const ushort4*)hWb;
    float4 acc = make_float4(0.f, 0.f, 0.f, 0.f);
    float ssum = 0.f;
    int s_next = (p0 < p1) ? esrc[p0] : 0;
    for (int p = p0; p < p1; ++p) {
        int s = s_next;
        if (p + 1 < p1) s_next = esrc[p + 1];
        float e = leaky(a_s[s] + ad, 0.2f);
        float ex = __expf(e);
        ssum += ex;
        ushort4 hv = hW4[(size_t)s * 32 + lane];
        acc.x = fmaf(ex, f_of_bf16(hv.x), acc.x);
        acc.y = fmaf(ex, f_of_bf16(hv.y), acc.y);
        acc.z = fmaf(ex, f_of_bf16(hv.z), acc.z);
        acc.w = fmaf(ex, f_of_bf16(hv.w), acc.w);
    }
    float inv = 1.f / (ssum + 1e-16f);
    float4 b4 = ((const float4*)bias)[lane];
    float4 o = make_float4(acc.x * inv + b4.x, acc.y * inv + b4.y,
                           acc.z * inv + b4.z, acc.w * inv + b4.w);
    ((float4*)hout)[(size_t)d * 32 + lane] = o;
}

// ---------------- GraphNorm: column stats ----------------
__global__ __launch_bounds__(256) void k_colstat(const float* __restrict__ h,
                                                 float* __restrict__ colsum,
                                                 float* __restrict__ colsq, int n) {
    int c = threadIdx.x & 127;
    int half = threadIdx.x >> 7;
    int rows_per = (n + gridDim.x - 1) / gridDim.x;
    int r0 = blockIdx.x * rows_per;
    int r1 = min(r0 + rows_per, n);
    float s = 0.f, q = 0.f;
    for (int r = r0 + half; r < r1; r += 2) {
        float v = h[(size_t)r * HD + c];
        s += v;
        q = fmaf(v, v, q);
    }
    atomicAdd(&colsum[c], s);
    atomicAdd(&colsq[c], q);
}

// per-column affine: alpha = w * rsqrt(var+eps); beta = b - mean*scale*alpha
__global__ void k_coeff(const float* __restrict__ colsum, const float* __restrict__ colsq,
                        const float* __restrict__ w, const float* __restrict__ b,
                        const float* __restrict__ ms, float* __restrict__ alpha,
                        float* __restrict__ beta, float inv_n) {
    int c = threadIdx.x;
    float mean = colsum[c] * inv_n;
    float ex2 = colsq[c] * inv_n;
    float m2 = mean * ms[c];
    float var = ex2 - 2.f * m2 * mean + m2 * m2;
    float a = w[c] * rsqrtf(var + 1e-5f);
    alpha[c] = a;
    beta[c] = b[c] - m2 * a;
}

// ---------------- global_add_pool (batch sorted -> run accumulation) ----------------
__global__ __launch_bounds__(256) void k_pool(const float* __restrict__ h,
                                              const int* __restrict__ batch,
                                              float* __restrict__ pooled, int n) {
    int c = threadIdx.x & 127;
    int half = threadIdx.x >> 7;
    int base = blockIdx.x * 64 + half * 32;
    float acc = 0.f;
    int cur = -1;
    for (int j = 0; j < 32; ++j) {
        int r = base + j;
        if (r >= n) break;
        int g = batch[r];
        if (g != cur) {
            if (cur >= 0) atomicAdd(&pooled[cur * HD + c], acc);
            acc = 0.f;
            cur = g;
        }
        acc += h[(size_t)r * HD + c];
    }
    if (cur >= 0) atomicAdd(&pooled[cur * HD + c], acc);
}

// ---------------- final MLP ----------------
__global__ __launch_bounds__(128) void k_mlp(const float* __restrict__ pooled,
                                             const float* __restrict__ W1,
                                             const float* __restrict__ b1,
                                             const float* __restrict__ W2,
                                             const float* __restrict__ b2,
                                             float* __restrict__ out) {
    __shared__ float pr[HD];
    __shared__ float zs[HD];
    int g = blockIdx.x, t = threadIdx.x;
    pr[t] = pooled[g * HD + t];
    __syncthreads();
    float acc = b1[t];
#pragma unroll 8
    for (int k = 0; k < HD; ++k) acc = fmaf(pr[k], W1[k * HD + t], acc);
    zs[t] = leaky(acc, 0.01f);
    __syncthreads();
    if (t < 64) {
        float a2 = b2[t];
#pragma unroll 8
        for (int k = 0; k < HD; ++k) a2 = fmaf(zs[k], W2[k * 64 + t], a2);
        out[g * 64 + t] = a2;
    }
}

extern "C" void kernel_launch(void* const* d_in, const int* in_sizes, int n_in,
                              void* d_out, int out_size, void* d_ws, size_t ws_size,
                              hipStream_t stream) {
    const float* x        = (const float*)d_in[0];
    const int*   ei       = (const int*)d_in[1];
    const int*   batch    = (const int*)d_in[2];
    const float* Ws       = (const float*)d_in[3];
    const float* att_src  = (const float*)d_in[4];
    const float* att_dst  = (const float*)d_in[5];
    const float* conv_bias= (const float*)d_in[6];
    const float* gn_w     = (const float*)d_in[7];
    const float* gn_b     = (const float*)d_in[8];
    const float* gn_ms    = (const float*)d_in[9];
    const float* W1       = (const float*)d_in[10];
    const float* b1       = (const float*)d_in[11];
    const float* W2       = (const float*)d_in[12];
    const float* b2       = (const float*)d_in[13];
    float* out = (float*)d_out;

    const int n = in_sizes[2];       // 100000
    const int e = in_sizes[1] / 2;   // 600000
    const int* src = ei;
    const int* dst = ei + e;

    char* ws = (char*)d_ws;
    unsigned short* hWb = (unsigned short*)ws;              // n*128 bf16
    float* h      = (float*)(ws + (size_t)n * 128 * 2);     // n*128 f32
    float* a_s    = h + (size_t)n * HD;                     // n
    float* a_d    = a_s + n;                                // n
    float* colsum = a_d + n;                                // 128
    float* colsq  = colsum + HD;                            // 128
    float* alpha  = colsq + HD;                             // 128
    float* beta   = alpha + HD;                             // 128
    float* pooled = beta + HD;                              // GG*HD
    unsigned short* Wt = (unsigned short*)(pooled + GG * HD); // 3*128*128 bf16
    int* counts   = (int*)(Wt + 3 * 16384);                 // n
    int* cursor   = counts + n;                             // n
    int* offs     = cursor + n;                             // n+1
    int* esrc     = offs + n + 1;                           // e
    int* bsums    = esrc + e;                               // 512
    int* boffs    = bsums + 512;                            // 512

    const int nb = (n + 255) / 256;

    // ---- weights -> bf16 (transposed), CSR build ----
    k_convW<<<192, 256, 0, stream>>>(Ws, Wt);
    k_zero_i32<<<(2 * n + 255) / 256, 256, 0, stream>>>(counts, 2 * n);
    k_count<<<(e + 255) / 256, 256, 0, stream>>>(dst, counts, e);
    k_scan_reduce<<<nb, 256, 0, stream>>>(counts, bsums, n);
    k_scan_top<<<1, 512, 0, stream>>>(bsums, boffs, nb, offs, n);
    k_scan_apply<<<nb, 256, 0, stream>>>(counts, boffs, offs, n);
    k_scatter<<<(e + 255) / 256, 256, 0, stream>>>(src, dst, offs, cursor, esrc, e);

    // ---- GAT layers ----
    const float* hin = x;
    for (int l = 0; l < 3; ++l) {
        k_gemm_mfma<<<(n + 127) / 128, 256, 0, stream>>>(
            hin, Wt + l * 16384, att_src + l * HD, att_dst + l * HD,
            alpha, beta, (l > 0) ? 1 : 0, hWb, a_s, a_d, n);
        k_agg<<<(n + 7) / 8, 256, 0, stream>>>(hWb, offs, esrc, a_s, a_d,
                                               conv_bias + l * HD, h, n);
        if (l < 2) {
            k_zero_f32<<<1, 256, 0, stream>>>(colsum, 2 * HD);  // colsum+colsq
            k_colstat<<<400, 256, 0, stream>>>(h, colsum, colsq, n);
            k_coeff<<<1, HD, 0, stream>>>(colsum, colsq, gn_w + l * HD, gn_b + l * HD,
                                          gn_ms + l * HD, alpha, beta, 1.0f / n);
        }
        hin = h;
    }

    // ---- pool + MLP ----
    k_zero_f32<<<(GG * HD + 255) / 256, 256, 0, stream>>>(pooled, GG * HD);
    k_pool<<<(n + 63) / 64, 256, 0, stream>>>(h, batch, pooled, n);
    k_mlp<<<GG, HD, 0, stream>>>(pooled, W1, b1, W2, b2, out);
}

// Round 3
// 532.308 us; speedup vs baseline: 3.0375x; 1.0002x over previous
//
#include <hip/hip_runtime.h>
#include <math.h>

#define HD 128
#define GG 64

typedef __attribute__((ext_vector_type(8))) short short8;
typedef __attribute__((ext_vector_type(4))) float f32x4;

__device__ __forceinline__ float leaky(float x, float s) { return x > 0.f ? x : s * x; }

__device__ __forceinline__ unsigned short bf16_of(float f) {
    union { float f; unsigned u; } v; v.f = f;
    unsigned r = v.u + 0x7fffu + ((v.u >> 16) & 1u);
    return (unsigned short)(r >> 16);
}
__device__ __forceinline__ float f_of_bf16(unsigned short u) {
    union { unsigned u; float f; } v; v.u = ((unsigned)u) << 16;
    return v.f;
}

// ---------------- zero fill ----------------
__global__ void k_zero_f32(float* p, int n) {
    int i = blockIdx.x * blockDim.x + threadIdx.x;
    if (i < n) p[i] = 0.f;
}
__global__ void k_zero_i32(int* p, int n) {
    int i = blockIdx.x * blockDim.x + threadIdx.x;
    if (i < n) p[i] = 0;
}

// ---------------- W -> Wt bf16 (transposed: Wt[l][n][k] = W[l][k][n]) ----------------
__global__ void k_convW(const float* __restrict__ Ws, unsigned short* __restrict__ Wt) {
    int i = blockIdx.x * 256 + threadIdx.x;
    if (i >= 3 * 16384) return;
    int l = i >> 14, rem = i & 16383;
    int nn = rem >> 7, k = rem & 127;
    Wt[i] = bf16_of(Ws[l * 16384 + k * 128 + nn]);
}

// ---------------- MFMA GEMM: hWb[n,128](bf16) = norm(A)[n,128] @ W ----------------
// Fused: optional GraphNorm affine+leaky on A load; a_s/a_d row-dot epilogue.
__global__ __launch_bounds__(256) void k_gemm_mfma(
    const float* __restrict__ A, const unsigned short* __restrict__ Wt,
    const float* __restrict__ att_s, const float* __restrict__ att_d,
    const float* __restrict__ alpha, const float* __restrict__ beta, int use_norm,
    unsigned short* __restrict__ hWb, float* __restrict__ a_s, float* __restrict__ a_d,
    int n) {
    __shared__ unsigned short As[128 * 128];
    __shared__ unsigned short Bs[128 * 128];
    const int tid = threadIdx.x;
    const int base = blockIdx.x * 128;

    const uint4* Wt4 = (const uint4*)Wt;
    uint4* Bs4 = (uint4*)Bs;
#pragma unroll
    for (int j = 0; j < 8; ++j) Bs4[tid + j * 256] = Wt4[tid + j * 256];

    const float4* A4 = (const float4*)A;
#pragma unroll
    for (int j = 0; j < 16; ++j) {
        int flat = tid + j * 256;           // 0..4095 float4 slots
        int r = flat >> 5, c4 = flat & 31;
        float4 v = make_float4(0.f, 0.f, 0.f, 0.f);
        if (base + r < n) v = A4[(size_t)(base + r) * 32 + c4];
        if (use_norm) {
            float4 al = ((const float4*)alpha)[c4];
            float4 be = ((const float4*)beta)[c4];
            v.x = leaky(fmaf(v.x, al.x, be.x), 0.01f);
            v.y = leaky(fmaf(v.y, al.y, be.y), 0.01f);
            v.z = leaky(fmaf(v.z, al.z, be.z), 0.01f);
            v.w = leaky(fmaf(v.w, al.w, be.w), 0.01f);
        }
        ushort4 b;
        b.x = bf16_of(v.x); b.y = bf16_of(v.y); b.z = bf16_of(v.z); b.w = bf16_of(v.w);
        *(ushort4*)&As[r * 128 + c4 * 4] = b;
    }
    __syncthreads();

    const int wave = tid >> 6;
    const int lane = tid & 63;
    const int m16 = lane & 15;
    const int quad = lane >> 4;

    f32x4 acc[2][8];
#pragma unroll
    for (int rt = 0; rt < 2; ++rt)
#pragma unroll
        for (int ct = 0; ct < 8; ++ct) acc[rt][ct] = (f32x4){0.f, 0.f, 0.f, 0.f};

#pragma unroll
    for (int kk = 0; kk < 4; ++kk) {      // K in steps of 32
        short8 af[2];
#pragma unroll
        for (int rt = 0; rt < 2; ++rt) {
            int row = wave * 32 + rt * 16 + m16;
            af[rt] = *(const short8*)&As[row * 128 + kk * 32 + quad * 8];
        }
#pragma unroll
        for (int ct = 0; ct < 8; ++ct) {
            int col = ct * 16 + m16;
            short8 bfr = *(const short8*)&Bs[col * 128 + kk * 32 + quad * 8];
            acc[0][ct] = __builtin_amdgcn_mfma_f32_16x16x32_bf16(af[0], bfr, acc[0][ct], 0, 0, 0);
            acc[1][ct] = __builtin_amdgcn_mfma_f32_16x16x32_bf16(af[1], bfr, acc[1][ct], 0, 0, 0);
        }
    }
    __syncthreads();   // As fully consumed; reuse as hW staging

    // epilogue: stash bf16 hW into As; fused a_s/a_d row dots from fp32 acc
#pragma unroll
    for (int rt = 0; rt < 2; ++rt) {
#pragma unroll
        for (int reg = 0; reg < 4; ++reg) {
            int lrow = wave * 32 + rt * 16 + quad * 4 + reg;
            float s = 0.f, dd = 0.f;
#pragma unroll
            for (int ct = 0; ct < 8; ++ct) {
                float v = acc[rt][ct][reg];
                int col = ct * 16 + m16;
                As[lrow * 128 + col] = bf16_of(v);
                s = fmaf(v, att_s[col], s);
                dd = fmaf(v, att_d[col], dd);
            }
#pragma unroll
            for (int off = 1; off < 16; off <<= 1) {
                s += __shfl_xor(s, off, 64);
                dd += __shfl_xor(dd, off, 64);
            }
            if (m16 == 0) {
                int gr = base + lrow;
                if (gr < n) { a_s[gr] = s; a_d[gr] = dd; }
            }
        }
    }
    __syncthreads();

    uint4* out4 = (uint4*)hWb;
    const uint4* AsC = (const uint4*)As;
#pragma unroll
    for (int j = 0; j < 8; ++j) {
        int flat = tid + j * 256;           // 2048 uint4 in tile
        int r = flat >> 4;
        if (base + r < n) out4[(size_t)base * 16 + flat] = AsC[flat];
    }
}

// ---------------- CSR build ----------------
__global__ void k_count(const int* __restrict__ dst, int* __restrict__ counts, int e) {
    int i = blockIdx.x * blockDim.x + threadIdx.x;
    if (i < e) atomicAdd(&counts[dst[i]], 1);
}

__global__ void k_scan_reduce(const int* __restrict__ counts, int* __restrict__ bsums, int n) {
    __shared__ int s[256];
    int tid = threadIdx.x;
    int i = blockIdx.x * 256 + tid;
    s[tid] = (i < n) ? counts[i] : 0;
    __syncthreads();
#pragma unroll
    for (int off = 128; off; off >>= 1) {
        if (tid < off) s[tid] += s[tid + off];
        __syncthreads();
    }
    if (tid == 0) bsums[blockIdx.x] = s[0];
}

__global__ void k_scan_top(const int* __restrict__ bsums, int* __restrict__ boffs,
                           int nb, int* __restrict__ offs, int n_nodes) {
    __shared__ int s[512];
    int tid = threadIdx.x;
    int own = (tid < nb) ? bsums[tid] : 0;
    s[tid] = own;
    __syncthreads();
    for (int off = 1; off < 512; off <<= 1) {
        int t = 0;
        if (tid >= off) t = s[tid - off];
        __syncthreads();
        s[tid] += t;
        __syncthreads();
    }
    if (tid < nb) boffs[tid] = s[tid] - own;
    if (tid == 511) offs[n_nodes] = s[511];
}

__global__ void k_scan_apply(const int* __restrict__ counts, const int* __restrict__ boffs,
                             int* __restrict__ offs, int n) {
    __shared__ int s[256];
    int tid = threadIdx.x;
    int i = blockIdx.x * 256 + tid;
    int own = (i < n) ? counts[i] : 0;
    s[tid] = own;
    __syncthreads();
    for (int off = 1; off < 256; off <<= 1) {
        int t = 0;
        if (tid >= off) t = s[tid - off];
        __syncthreads();
        s[tid] += t;
        __syncthreads();
    }
    if (i < n) offs[i] = boffs[blockIdx.x] + s[tid] - own;
}

__global__ void k_scatter(const int* __restrict__ src, const int* __restrict__ dst,
                          const int* __restrict__ offs, int* __restrict__ cursor,
                          int* __restrict__ esrc, int e) {
    int i = blockIdx.x * blockDim.x + threadIdx.x;
    if (i < e) {
        int d = dst[i];
        int pos = offs[d] + atomicAdd(&cursor[d], 1);
        esrc[pos] = src[i];
    }
}

// ---------------- fused attention softmax + aggregation (bf16 hW gather) ----------------
// One 64-lane wave per dst node; halves process alternating edges (2 gathers in flight).
__global__ __launch_bounds__(256) void k_agg(const unsigned short* __restrict__ hWb,
                                             const int* __restrict__ offs,
                                             const int* __restrict__ esrc,
                                             const float* __restrict__ a_s,
                                             const float* __restrict__ a_d,
                                             const float* __restrict__ bias,
                                             float* __restrict__ hout, int n) {
    int d = blockIdx.x * 4 + (threadIdx.x >> 6);
    int lane = threadIdx.x & 63;
    int half = lane >> 5;
    int l32 = lane & 31;
    if (d >= n) return;
    int p0 = offs[d], p1 = offs[d + 1];
    float ad = a_d[d];
    const ushort4* hW4 = (const ushort4*)hWb;
    float4 acc = make_float4(0.f, 0.f, 0.f, 0.f);
    float ssum = 0.f;
    for (int p = p0 + half; p < p1; p += 2) {
        int s = esrc[p];
        float e = leaky(a_s[s] + ad, 0.2f);
        float ex = __expf(e);
        ssum += ex;
        ushort4 hv = hW4[(size_t)s * 32 + l32];
        acc.x = fmaf(ex, f_of_bf16(hv.x), acc.x);
        acc.y = fmaf(ex, f_of_bf16(hv.y), acc.y);
        acc.z = fmaf(ex, f_of_bf16(hv.z), acc.z);
        acc.w = fmaf(ex, f_of_bf16(hv.w), acc.w);
    }
    // merge halves (lane ^ 32)
    ssum += __shfl_xor(ssum, 32, 64);
    acc.x += __shfl_xor(acc.x, 32, 64);
    acc.y += __shfl_xor(acc.y, 32, 64);
    acc.z += __shfl_xor(acc.z, 32, 64);
    acc.w += __shfl_xor(acc.w, 32, 64);
    if (half == 0) {
        float inv = 1.f / (ssum + 1e-16f);
        float4 b4 = ((const float4*)bias)[l32];
        float4 o = make_float4(acc.x * inv + b4.x, acc.y * inv + b4.y,
                               acc.z * inv + b4.z, acc.w * inv + b4.w);
        ((float4*)hout)[(size_t)d * 32 + l32] = o;
    }
}

// ---------------- GraphNorm stats, stage A: vectorized grid-stride partials ----------------
// 256 blocks x 256 threads, float4 loads; per-block LDS reduce to 32 float4 partials.
__global__ __launch_bounds__(256) void k_colstat2(const float* __restrict__ h,
                                                  float4* __restrict__ ps,
                                                  float4* __restrict__ pq, int n) {
    const float4* h4 = (const float4*)h;
    const int tid = threadIdx.x;
    const int total = n * 32;
    float4 s = make_float4(0.f, 0.f, 0.f, 0.f);
    float4 q = make_float4(0.f, 0.f, 0.f, 0.f);
    for (int i = blockIdx.x * 256 + tid; i < total; i += 256 * 256) {
        float4 v = h4[i];   // (i & 31) == (tid & 31): column group fixed per thread
        s.x += v.x; s.y += v.y; s.z += v.z; s.w += v.w;
        q.x = fmaf(v.x, v.x, q.x);
        q.y = fmaf(v.y, v.y, q.y);
        q.z = fmaf(v.z, v.z, q.z);
        q.w = fmaf(v.w, v.w, q.w);
    }
    __shared__ float4 ss[256];
    __shared__ float4 sq[256];
    ss[tid] = s; sq[tid] = q;
    __syncthreads();
    if (tid < 32) {
        float4 S = ss[tid], Q = sq[tid];
#pragma unroll
        for (int k = 1; k < 8; ++k) {
            float4 a = ss[tid + 32 * k];
            float4 b = sq[tid + 32 * k];
            S.x += a.x; S.y += a.y; S.z += a.z; S.w += a.w;
            Q.x += b.x; Q.y += b.y; Q.z += b.z; Q.w += b.w;
        }
        ps[blockIdx.x * 32 + tid] = S;
        pq[blockIdx.x * 32 + tid] = Q;
    }
}

// ---------------- stage B: reduce partials + compute alpha/beta (absorbs k_coeff) ----------------
__global__ void k_colfinish(const float4* __restrict__ ps, const float4* __restrict__ pq,
                            const float* __restrict__ w, const float* __restrict__ bb,
                            const float* __restrict__ ms, float* __restrict__ alpha,
                            float* __restrict__ beta, float inv_n) {
    int t = threadIdx.x;          // 64 launched, 32 used
    if (t >= 32) return;
    float4 S = make_float4(0.f, 0.f, 0.f, 0.f);
    float4 Q = make_float4(0.f, 0.f, 0.f, 0.f);
    for (int b = 0; b < 256; ++b) {
        float4 a = ps[b * 32 + t];
        float4 c = pq[b * 32 + t];
        S.x += a.x; S.y += a.y; S.z += a.z; S.w += a.w;
        Q.x += c.x; Q.y += c.y; Q.z += c.z; Q.w += c.w;
    }
    float sv[4] = {S.x, S.y, S.z, S.w};
    float qv[4] = {Q.x, Q.y, Q.z, Q.w};
#pragma unroll
    for (int k = 0; k < 4; ++k) {
        int c = t * 4 + k;
        float mean = sv[k] * inv_n;
        float ex2 = qv[k] * inv_n;
        float m2 = mean * ms[c];
        float var = ex2 - 2.f * m2 * mean + m2 * m2;
        float a = w[c] * rsqrtf(var + 1e-5f);
        alpha[c] = a;
        beta[c] = bb[c] - m2 * a;
    }
}

// ---------------- global_add_pool (batch sorted -> run accumulation) ----------------
__global__ __launch_bounds__(256) void k_pool(const float* __restrict__ h,
                                              const int* __restrict__ batch,
                                              float* __restrict__ pooled, int n) {
    int c = threadIdx.x & 127;
    int half = threadIdx.x >> 7;
    int base = blockIdx.x * 64 + half * 32;
    float acc = 0.f;
    int cur = -1;
    for (int j = 0; j < 32; ++j) {
        int r = base + j;
        if (r >= n) break;
        int g = batch[r];
        if (g != cur) {
            if (cur >= 0) atomicAdd(&pooled[cur * HD + c], acc);
            acc = 0.f;
            cur = g;
        }
        acc += h[(size_t)r * HD + c];
    }
    if (cur >= 0) atomicAdd(&pooled[cur * HD + c], acc);
}

// ---------------- final MLP ----------------
__global__ __launch_bounds__(128) void k_mlp(const float* __restrict__ pooled,
                                             const float* __restrict__ W1,
                                             const float* __restrict__ b1,
                                             const float* __restrict__ W2,
                                             const float* __restrict__ b2,
                                             float* __restrict__ out) {
    __shared__ float pr[HD];
    __shared__ float zs[HD];
    int g = blockIdx.x, t = threadIdx.x;
    pr[t] = pooled[g * HD + t];
    __syncthreads();
    float acc = b1[t];
#pragma unroll 8
    for (int k = 0; k < HD; ++k) acc = fmaf(pr[k], W1[k * HD + t], acc);
    zs[t] = leaky(acc, 0.01f);
    __syncthreads();
    if (t < 64) {
        float a2 = b2[t];
#pragma unroll 8
        for (int k = 0; k < HD; ++k) a2 = fmaf(zs[k], W2[k * 64 + t], a2);
        out[g * 64 + t] = a2;
    }
}

extern "C" void kernel_launch(void* const* d_in, const int* in_sizes, int n_in,
                              void* d_out, int out_size, void* d_ws, size_t ws_size,
                              hipStream_t stream) {
    const float* x        = (const float*)d_in[0];
    const int*   ei       = (const int*)d_in[1];
    const int*   batch    = (const int*)d_in[2];
    const float* Ws       = (const float*)d_in[3];
    const float* att_src  = (const float*)d_in[4];
    const float* att_dst  = (const float*)d_in[5];
    const float* conv_bias= (const float*)d_in[6];
    const float* gn_w     = (const float*)d_in[7];
    const float* gn_b     = (const float*)d_in[8];
    const float* gn_ms    = (const float*)d_in[9];
    const float* W1       = (const float*)d_in[10];
    const float* b1       = (const float*)d_in[11];
    const float* W2       = (const float*)d_in[12];
    const float* b2       = (const float*)d_in[13];
    float* out = (float*)d_out;

    const int n = in_sizes[2];       // 100000
    const int e = in_sizes[1] / 2;   // 600000
    const int* src = ei;
    const int* dst = ei + e;

    char* ws = (char*)d_ws;
    unsigned short* hWb = (unsigned short*)ws;              // n*128 bf16
    float* h      = (float*)(ws + (size_t)n * 128 * 2);     // n*128 f32
    float* a_s    = h + (size_t)n * HD;                     // n
    float* a_d    = a_s + n;                                // n
    float* alpha  = a_d + n;                                // 128
    float* beta   = alpha + HD;                             // 128
    float* pooled = beta + HD;                              // GG*HD
    float4* ps    = (float4*)(pooled + GG * HD);            // 256*32 float4
    float4* pq    = ps + 256 * 32;                          // 256*32 float4
    unsigned short* Wt = (unsigned short*)(pq + 256 * 32);  // 3*128*128 bf16
    int* counts   = (int*)(Wt + 3 * 16384);                 // n
    int* cursor   = counts + n;                             // n
    int* offs     = cursor + n;                             // n+1
    int* esrc     = offs + n + 1;                           // e
    int* bsums    = esrc + e;                               // 512
    int* boffs    = bsums + 512;                            // 512

    const int nb = (n + 255) / 256;

    // ---- weights -> bf16 (transposed), CSR build ----
    k_convW<<<192, 256, 0, stream>>>(Ws, Wt);
    k_zero_i32<<<(2 * n + 255) / 256, 256, 0, stream>>>(counts, 2 * n);
    k_count<<<(e + 255) / 256, 256, 0, stream>>>(dst, counts, e);
    k_scan_reduce<<<nb, 256, 0, stream>>>(counts, bsums, n);
    k_scan_top<<<1, 512, 0, stream>>>(bsums, boffs, nb, offs, n);
    k_scan_apply<<<nb, 256, 0, stream>>>(counts, boffs, offs, n);
    k_scatter<<<(e + 255) / 256, 256, 0, stream>>>(src, dst, offs, cursor, esrc, e);

    // ---- GAT layers ----
    const float* hin = x;
    for (int l = 0; l < 3; ++l) {
        k_gemm_mfma<<<(n + 127) / 128, 256, 0, stream>>>(
            hin, Wt + l * 16384, att_src + l * HD, att_dst + l * HD,
            alpha, beta, (l > 0) ? 1 : 0, hWb, a_s, a_d, n);
        k_agg<<<(n + 3) / 4, 256, 0, stream>>>(hWb, offs, esrc, a_s, a_d,
                                               conv_bias + l * HD, h, n);
        if (l < 2) {
            k_colstat2<<<256, 256, 0, stream>>>(h, ps, pq, n);
            k_colfinish<<<1, 64, 0, stream>>>(ps, pq, gn_w + l * HD, gn_b + l * HD,
                                              gn_ms + l * HD, alpha, beta, 1.0f / n);
        }
        hin = h;
    }

    // ---- pool + MLP ----
    k_zero_f32<<<(GG * HD + 255) / 256, 256, 0, stream>>>(pooled, GG * HD);
    k_pool<<<(n + 63) / 64, 256, 0, stream>>>(h, batch, pooled, n);
    k_mlp<<<GG, HD, 0, stream>>>(pooled, W1, b1, W2, b2, out);
}

// Round 4
// 484.233 us; speedup vs baseline: 3.3390x; 1.0993x over previous
//
#include <hip/hip_runtime.h>
#include <math.h>

#define HD 128
#define GG 64

typedef __attribute__((ext_vector_type(8))) short short8;
typedef __attribute__((ext_vector_type(4))) float f32x4;

__device__ __forceinline__ float leaky(float x, float s) { return x > 0.f ? x : s * x; }

__device__ __forceinline__ unsigned short bf16_of(float f) {
    union { float f; unsigned u; } v; v.f = f;
    unsigned r = v.u + 0x7fffu + ((v.u >> 16) & 1u);
    return (unsigned short)(r >> 16);
}
__device__ __forceinline__ float f_of_bf16(unsigned short u) {
    union { unsigned u; float f; } v; v.u = ((unsigned)u) << 16;
    return v.f;
}

// ---------------- init: W->Wt bf16 transposed + zero counts/cursor ----------------
__global__ void k_init(const float* __restrict__ Ws, unsigned short* __restrict__ Wt,
                       int* __restrict__ counts2, int n2) {
    int i = blockIdx.x * 256 + threadIdx.x;
    if (i < 3 * 16384) {
        int l = i >> 14, rem = i & 16383;
        int nn = rem >> 7, k = rem & 127;
        Wt[i] = bf16_of(Ws[l * 16384 + k * 128 + nn]);
    }
    if (i < n2) counts2[i] = 0;
}

// ================= MFMA GEMM core (shared via macro-ish duplication) =============
// Block: 128 rows x 128 cols, 256 threads (4 waves). LDS 64KB -> 2 blocks/CU.
// Epilogue: bf16 hW store + fused a_s/a_d row dots.

// ---- variant A: fp32 input (layer 0, no norm) ----
__global__ __launch_bounds__(256) void k_gemm_a32(
    const float* __restrict__ A, const unsigned short* __restrict__ Wt,
    const float* __restrict__ att_s, const float* __restrict__ att_d,
    unsigned short* __restrict__ hWb, float* __restrict__ a_s, float* __restrict__ a_d,
    int n) {
    __shared__ unsigned short As[128 * 128];
    __shared__ unsigned short Bs[128 * 128];
    const int tid = threadIdx.x;
    const int base = blockIdx.x * 128;

    const uint4* Wt4 = (const uint4*)Wt;
    uint4* Bs4 = (uint4*)Bs;
#pragma unroll
    for (int j = 0; j < 8; ++j) Bs4[tid + j * 256] = Wt4[tid + j * 256];

    const float4* A4 = (const float4*)A;
#pragma unroll
    for (int j = 0; j < 16; ++j) {
        int flat = tid + j * 256;           // 4096 float4 slots
        int r = flat >> 5, c4 = flat & 31;
        float4 v = make_float4(0.f, 0.f, 0.f, 0.f);
        if (base + r < n) v = A4[(size_t)(base + r) * 32 + c4];
        ushort4 b;
        b.x = bf16_of(v.x); b.y = bf16_of(v.y); b.z = bf16_of(v.z); b.w = bf16_of(v.w);
        *(ushort4*)&As[r * 128 + c4 * 4] = b;
    }
    __syncthreads();

    const int wave = tid >> 6, lane = tid & 63;
    const int m16 = lane & 15, quad = lane >> 4;
    f32x4 acc[2][8];
#pragma unroll
    for (int rt = 0; rt < 2; ++rt)
#pragma unroll
        for (int ct = 0; ct < 8; ++ct) acc[rt][ct] = (f32x4){0.f, 0.f, 0.f, 0.f};
#pragma unroll
    for (int kk = 0; kk < 4; ++kk) {
        short8 af[2];
#pragma unroll
        for (int rt = 0; rt < 2; ++rt)
            af[rt] = *(const short8*)&As[(wave * 32 + rt * 16 + m16) * 128 + kk * 32 + quad * 8];
#pragma unroll
        for (int ct = 0; ct < 8; ++ct) {
            short8 bfr = *(const short8*)&Bs[(ct * 16 + m16) * 128 + kk * 32 + quad * 8];
            acc[0][ct] = __builtin_amdgcn_mfma_f32_16x16x32_bf16(af[0], bfr, acc[0][ct], 0, 0, 0);
            acc[1][ct] = __builtin_amdgcn_mfma_f32_16x16x32_bf16(af[1], bfr, acc[1][ct], 0, 0, 0);
        }
    }
    __syncthreads();
#pragma unroll
    for (int rt = 0; rt < 2; ++rt) {
#pragma unroll
        for (int reg = 0; reg < 4; ++reg) {
            int lrow = wave * 32 + rt * 16 + quad * 4 + reg;
            float s = 0.f, dd = 0.f;
#pragma unroll
            for (int ct = 0; ct < 8; ++ct) {
                float v = acc[rt][ct][reg];
                int col = ct * 16 + m16;
                As[lrow * 128 + col] = bf16_of(v);
                s = fmaf(v, att_s[col], s);
                dd = fmaf(v, att_d[col], dd);
            }
#pragma unroll
            for (int off = 1; off < 16; off <<= 1) {
                s += __shfl_xor(s, off, 64);
                dd += __shfl_xor(dd, off, 64);
            }
            if (m16 == 0) {
                int gr = base + lrow;
                if (gr < n) { a_s[gr] = s; a_d[gr] = dd; }
            }
        }
    }
    __syncthreads();
    uint4* out4 = (uint4*)hWb;
    const uint4* AsC = (const uint4*)As;
#pragma unroll
    for (int j = 0; j < 8; ++j) {
        int flat = tid + j * 256;
        int r = flat >> 4;
        if (base + r < n) out4[(size_t)base * 16 + flat] = AsC[flat];
    }
}

// ---- variant B: bf16 input + GraphNorm affine + leaky (layers 1,2) ----
__global__ __launch_bounds__(256) void k_gemm_a16(
    const unsigned short* __restrict__ Ab, const unsigned short* __restrict__ Wt,
    const float* __restrict__ att_s, const float* __restrict__ att_d,
    const float* __restrict__ alpha, const float* __restrict__ beta,
    unsigned short* __restrict__ hWb, float* __restrict__ a_s, float* __restrict__ a_d,
    int n) {
    __shared__ unsigned short As[128 * 128];
    __shared__ unsigned short Bs[128 * 128];
    const int tid = threadIdx.x;
    const int base = blockIdx.x * 128;

    const uint4* Wt4 = (const uint4*)Wt;
    uint4* Bs4 = (uint4*)Bs;
#pragma unroll
    for (int j = 0; j < 8; ++j) Bs4[tid + j * 256] = Wt4[tid + j * 256];

    const uint4* A4 = (const uint4*)Ab;   // 8 bf16 per uint4
    const float4* al4 = (const float4*)alpha;
    const float4* be4 = (const float4*)beta;
#pragma unroll
    for (int j = 0; j < 8; ++j) {
        int flat = tid + j * 256;           // 2048 uint4 slots (128 rows x 16)
        int r = flat >> 4, c8 = flat & 15;
        uint4 raw = make_uint4(0u, 0u, 0u, 0u);
        if (base + r < n) raw = A4[(size_t)(base + r) * 16 + c8];
        float4 a0 = al4[c8 * 2], a1 = al4[c8 * 2 + 1];
        float4 b0 = be4[c8 * 2], b1 = be4[c8 * 2 + 1];
        float f0 = leaky(fmaf(f_of_bf16(raw.x & 0xffff), a0.x, b0.x), 0.01f);
        float f1 = leaky(fmaf(f_of_bf16(raw.x >> 16),    a0.y, b0.y), 0.01f);
        float f2 = leaky(fmaf(f_of_bf16(raw.y & 0xffff), a0.z, b0.z), 0.01f);
        float f3 = leaky(fmaf(f_of_bf16(raw.y >> 16),    a0.w, b0.w), 0.01f);
        float f4 = leaky(fmaf(f_of_bf16(raw.z & 0xffff), a1.x, b1.x), 0.01f);
        float f5 = leaky(fmaf(f_of_bf16(raw.z >> 16),    a1.y, b1.y), 0.01f);
        float f6 = leaky(fmaf(f_of_bf16(raw.w & 0xffff), a1.z, b1.z), 0.01f);
        float f7 = leaky(fmaf(f_of_bf16(raw.w >> 16),    a1.w, b1.w), 0.01f);
        uint4 pk;
        pk.x = (unsigned)bf16_of(f0) | ((unsigned)bf16_of(f1) << 16);
        pk.y = (unsigned)bf16_of(f2) | ((unsigned)bf16_of(f3) << 16);
        pk.z = (unsigned)bf16_of(f4) | ((unsigned)bf16_of(f5) << 16);
        pk.w = (unsigned)bf16_of(f6) | ((unsigned)bf16_of(f7) << 16);
        *(uint4*)&As[r * 128 + c8 * 8] = pk;
    }
    __syncthreads();

    const int wave = tid >> 6, lane = tid & 63;
    const int m16 = lane & 15, quad = lane >> 4;
    f32x4 acc[2][8];
#pragma unroll
    for (int rt = 0; rt < 2; ++rt)
#pragma unroll
        for (int ct = 0; ct < 8; ++ct) acc[rt][ct] = (f32x4){0.f, 0.f, 0.f, 0.f};
#pragma unroll
    for (int kk = 0; kk < 4; ++kk) {
        short8 af[2];
#pragma unroll
        for (int rt = 0; rt < 2; ++rt)
            af[rt] = *(const short8*)&As[(wave * 32 + rt * 16 + m16) * 128 + kk * 32 + quad * 8];
#pragma unroll
        for (int ct = 0; ct < 8; ++ct) {
            short8 bfr = *(const short8*)&Bs[(ct * 16 + m16) * 128 + kk * 32 + quad * 8];
            acc[0][ct] = __builtin_amdgcn_mfma_f32_16x16x32_bf16(af[0], bfr, acc[0][ct], 0, 0, 0);
            acc[1][ct] = __builtin_amdgcn_mfma_f32_16x16x32_bf16(af[1], bfr, acc[1][ct], 0, 0, 0);
        }
    }
    __syncthreads();
#pragma unroll
    for (int rt = 0; rt < 2; ++rt) {
#pragma unroll
        for (int reg = 0; reg < 4; ++reg) {
            int lrow = wave * 32 + rt * 16 + quad * 4 + reg;
            float s = 0.f, dd = 0.f;
#pragma unroll
            for (int ct = 0; ct < 8; ++ct) {
                float v = acc[rt][ct][reg];
                int col = ct * 16 + m16;
                As[lrow * 128 + col] = bf16_of(v);
                s = fmaf(v, att_s[col], s);
                dd = fmaf(v, att_d[col], dd);
            }
#pragma unroll
            for (int off = 1; off < 16; off <<= 1) {
                s += __shfl_xor(s, off, 64);
                dd += __shfl_xor(dd, off, 64);
            }
            if (m16 == 0) {
                int gr = base + lrow;
                if (gr < n) { a_s[gr] = s; a_d[gr] = dd; }
            }
        }
    }
    __syncthreads();
    uint4* out4 = (uint4*)hWb;
    const uint4* AsC = (const uint4*)As;
#pragma unroll
    for (int j = 0; j < 8; ++j) {
        int flat = tid + j * 256;
        int r = flat >> 4;
        if (base + r < n) out4[(size_t)base * 16 + flat] = AsC[flat];
    }
}

// ---------------- CSR build ----------------
__global__ void k_count(const int* __restrict__ dst, int* __restrict__ counts, int e) {
    int i = blockIdx.x * blockDim.x + threadIdx.x;
    if (i < e) atomicAdd(&counts[dst[i]], 1);
}

__global__ void k_scan_reduce(const int* __restrict__ counts, int* __restrict__ bsums, int n) {
    __shared__ int s[256];
    int tid = threadIdx.x;
    int i = blockIdx.x * 256 + tid;
    s[tid] = (i < n) ? counts[i] : 0;
    __syncthreads();
#pragma unroll
    for (int off = 128; off; off >>= 1) {
        if (tid < off) s[tid] += s[tid + off];
        __syncthreads();
    }
    if (tid == 0) bsums[blockIdx.x] = s[0];
}

__global__ void k_scan_top(const int* __restrict__ bsums, int* __restrict__ boffs,
                           int nb, int* __restrict__ offs, int n_nodes) {
    __shared__ int s[512];
    int tid = threadIdx.x;
    int own = (tid < nb) ? bsums[tid] : 0;
    s[tid] = own;
    __syncthreads();
    for (int off = 1; off < 512; off <<= 1) {
        int t = 0;
        if (tid >= off) t = s[tid - off];
        __syncthreads();
        s[tid] += t;
        __syncthreads();
    }
    if (tid < nb) boffs[tid] = s[tid] - own;
    if (tid == 511) offs[n_nodes] = s[511];
}

__global__ void k_scan_apply(const int* __restrict__ counts, const int* __restrict__ boffs,
                             int* __restrict__ offs, int n) {
    __shared__ int s[256];
    int tid = threadIdx.x;
    int i = blockIdx.x * 256 + tid;
    int own = (i < n) ? counts[i] : 0;
    s[tid] = own;
    __syncthreads();
    for (int off = 1; off < 256; off <<= 1) {
        int t = 0;
        if (tid >= off) t = s[tid - off];
        __syncthreads();
        s[tid] += t;
        __syncthreads();
    }
    if (i < n) offs[i] = boffs[blockIdx.x] + s[tid] - own;
}

__global__ void k_scatter(const int* __restrict__ src, const int* __restrict__ dst,
                          const int* __restrict__ offs, int* __restrict__ cursor,
                          int* __restrict__ esrc, int e) {
    int i = blockIdx.x * blockDim.x + threadIdx.x;
    if (i < e) {
        int d = dst[i];
        int pos = offs[d] + atomicAdd(&cursor[d], 1);
        esrc[pos] = src[i];
    }
}

// ---------------- fused attention softmax + aggregation -> bf16 h ----------------
__global__ __launch_bounds__(256) void k_agg(const unsigned short* __restrict__ hWb,
                                             const int* __restrict__ offs,
                                             const int* __restrict__ esrc,
                                             const float* __restrict__ a_s,
                                             const float* __restrict__ a_d,
                                             const float* __restrict__ bias,
                                             unsigned short* __restrict__ hb, int n) {
    int d = blockIdx.x * 4 + (threadIdx.x >> 6);
    int lane = threadIdx.x & 63;
    int half = lane >> 5;
    int l32 = lane & 31;
    if (d >= n) return;
    int p0 = offs[d], p1 = offs[d + 1];
    float ad = a_d[d];
    const ushort4* hW4 = (const ushort4*)hWb;
    float4 acc = make_float4(0.f, 0.f, 0.f, 0.f);
    float ssum = 0.f;
    int s_cur = (p0 + half < p1) ? esrc[p0 + half] : 0;
    for (int p = p0 + half; p < p1; p += 2) {
        int s = s_cur;
        if (p + 2 < p1) s_cur = esrc[p + 2];
        float e = leaky(a_s[s] + ad, 0.2f);
        float ex = __expf(e);
        ssum += ex;
        ushort4 hv = hW4[(size_t)s * 32 + l32];
        acc.x = fmaf(ex, f_of_bf16(hv.x), acc.x);
        acc.y = fmaf(ex, f_of_bf16(hv.y), acc.y);
        acc.z = fmaf(ex, f_of_bf16(hv.z), acc.z);
        acc.w = fmaf(ex, f_of_bf16(hv.w), acc.w);
    }
    ssum += __shfl_xor(ssum, 32, 64);
    acc.x += __shfl_xor(acc.x, 32, 64);
    acc.y += __shfl_xor(acc.y, 32, 64);
    acc.z += __shfl_xor(acc.z, 32, 64);
    acc.w += __shfl_xor(acc.w, 32, 64);
    if (half == 0) {
        float inv = 1.f / (ssum + 1e-16f);
        float4 b4 = ((const float4*)bias)[l32];
        ushort4 o;
        o.x = bf16_of(acc.x * inv + b4.x);
        o.y = bf16_of(acc.y * inv + b4.y);
        o.z = bf16_of(acc.z * inv + b4.z);
        o.w = bf16_of(acc.w * inv + b4.w);
        ((ushort4*)hb)[(size_t)d * 32 + l32] = o;
    }
}

// ---------------- GraphNorm stats stage A (bf16 input) ----------------
__global__ __launch_bounds__(256) void k_colstat2(const unsigned short* __restrict__ hb,
                                                  float4* __restrict__ ps,
                                                  float4* __restrict__ pq, int n) {
    const ushort4* h4 = (const ushort4*)hb;
    const int tid = threadIdx.x;
    const int total = n * 32;
    float4 s = make_float4(0.f, 0.f, 0.f, 0.f);
    float4 q = make_float4(0.f, 0.f, 0.f, 0.f);
    for (int i = blockIdx.x * 256 + tid; i < total; i += 256 * 256) {
        ushort4 hv = h4[i];   // (i & 31) == (tid & 31): fixed column group
        float vx = f_of_bf16(hv.x), vy = f_of_bf16(hv.y);
        float vz = f_of_bf16(hv.z), vw = f_of_bf16(hv.w);
        s.x += vx; s.y += vy; s.z += vz; s.w += vw;
        q.x = fmaf(vx, vx, q.x);
        q.y = fmaf(vy, vy, q.y);
        q.z = fmaf(vz, vz, q.z);
        q.w = fmaf(vw, vw, q.w);
    }
    __shared__ float4 ss[256];
    __shared__ float4 sq[256];
    ss[tid] = s; sq[tid] = q;
    __syncthreads();
    if (tid < 32) {
        float4 S = ss[tid], Q = sq[tid];
#pragma unroll
        for (int k = 1; k < 8; ++k) {
            float4 a = ss[tid + 32 * k];
            float4 b = sq[tid + 32 * k];
            S.x += a.x; S.y += a.y; S.z += a.z; S.w += a.w;
            Q.x += b.x; Q.y += b.y; Q.z += b.z; Q.w += b.w;
        }
        ps[blockIdx.x * 32 + tid] = S;
        pq[blockIdx.x * 32 + tid] = Q;
    }
}

// ---------------- stage B: reduce partials + alpha/beta ----------------
__global__ void k_colfinish(const float4* __restrict__ ps, const float4* __restrict__ pq,
                            const float* __restrict__ w, const float* __restrict__ bb,
                            const float* __restrict__ ms, float* __restrict__ alpha,
                            float* __restrict__ beta, float inv_n) {
    int t = threadIdx.x;
    if (t >= 32) return;
    float4 S = make_float4(0.f, 0.f, 0.f, 0.f);
    float4 Q = make_float4(0.f, 0.f, 0.f, 0.f);
    for (int b = 0; b < 256; ++b) {
        float4 a = ps[b * 32 + t];
        float4 c = pq[b * 32 + t];
        S.x += a.x; S.y += a.y; S.z += a.z; S.w += a.w;
        Q.x += c.x; Q.y += c.y; Q.z += c.z; Q.w += c.w;
    }
    float sv[4] = {S.x, S.y, S.z, S.w};
    float qv[4] = {Q.x, Q.y, Q.z, Q.w};
#pragma unroll
    for (int k = 0; k < 4; ++k) {
        int c = t * 4 + k;
        float mean = sv[k] * inv_n;
        float ex2 = qv[k] * inv_n;
        float m2 = mean * ms[c];
        float var = ex2 - 2.f * m2 * mean + m2 * m2;
        float a = w[c] * rsqrtf(var + 1e-5f);
        alpha[c] = a;
        beta[c] = bb[c] - m2 * a;
    }
}

// ---------------- global_add_pool: 4 blocks/graph, binary search, no atomics ----------------
__device__ __forceinline__ int lower_bound_i(const int* __restrict__ a, int n, int key) {
    int lo = 0, hi = n;
    while (lo < hi) {
        int mid = (lo + hi) >> 1;
        if (a[mid] < key) lo = mid + 1; else hi = mid;
    }
    return lo;
}

__global__ __launch_bounds__(256) void k_pool(const unsigned short* __restrict__ hb,
                                              const int* __restrict__ batch,
                                              float* __restrict__ pooled4, int n) {
    int g = blockIdx.x >> 2, t4 = blockIdx.x & 3;
    int lo = lower_bound_i(batch, n, g);
    int hi = lower_bound_i(batch, n, g + 1);
    int len = hi - lo;
    int q = (len + 3) >> 2;
    int r0 = lo + t4 * q;
    int r1 = min(r0 + q, hi);
    int c4 = threadIdx.x & 31, rg = threadIdx.x >> 5;
    const ushort4* h4 = (const ushort4*)hb;
    float4 acc = make_float4(0.f, 0.f, 0.f, 0.f);
    for (int r = r0 + rg; r < r1; r += 8) {
        ushort4 hv = h4[(size_t)r * 32 + c4];
        acc.x += f_of_bf16(hv.x);
        acc.y += f_of_bf16(hv.y);
        acc.z += f_of_bf16(hv.z);
        acc.w += f_of_bf16(hv.w);
    }
    __shared__ float4 sred[256];
    sred[threadIdx.x] = acc;
    __syncthreads();
    if (threadIdx.x < 32) {
        float4 S = sred[threadIdx.x];
#pragma unroll
        for (int k = 1; k < 8; ++k) {
            float4 a = sred[threadIdx.x + 32 * k];
            S.x += a.x; S.y += a.y; S.z += a.z; S.w += a.w;
        }
        ((float4*)pooled4)[(t4 * GG + g) * 32 + threadIdx.x] = S;
    }
}

// ---------------- final MLP (sums the 4 pool partials) ----------------
__global__ __launch_bounds__(128) void k_mlp(const float* __restrict__ pooled4,
                                             const float* __restrict__ W1,
                                             const float* __restrict__ b1,
                                             const float* __restrict__ W2,
                                             const float* __restrict__ b2,
                                             float* __restrict__ out) {
    __shared__ float pr[HD];
    __shared__ float zs[HD];
    int g = blockIdx.x, t = threadIdx.x;
    float pv = 0.f;
#pragma unroll
    for (int k = 0; k < 4; ++k) pv += pooled4[(k * GG + g) * HD + t];
    pr[t] = pv;
    __syncthreads();
    float acc = b1[t];
#pragma unroll 8
    for (int k = 0; k < HD; ++k) acc = fmaf(pr[k], W1[k * HD + t], acc);
    zs[t] = leaky(acc, 0.01f);
    __syncthreads();
    if (t < 64) {
        float a2 = b2[t];
#pragma unroll 8
        for (int k = 0; k < HD; ++k) a2 = fmaf(zs[k], W2[k * 64 + t], a2);
        out[g * 64 + t] = a2;
    }
}

extern "C" void kernel_launch(void* const* d_in, const int* in_sizes, int n_in,
                              void* d_out, int out_size, void* d_ws, size_t ws_size,
                              hipStream_t stream) {
    const float* x        = (const float*)d_in[0];
    const int*   ei       = (const int*)d_in[1];
    const int*   batch    = (const int*)d_in[2];
    const float* Ws       = (const float*)d_in[3];
    const float* att_src  = (const float*)d_in[4];
    const float* att_dst  = (const float*)d_in[5];
    const float* conv_bias= (const float*)d_in[6];
    const float* gn_w     = (const float*)d_in[7];
    const float* gn_b     = (const float*)d_in[8];
    const float* gn_ms    = (const float*)d_in[9];
    const float* W1       = (const float*)d_in[10];
    const float* b1       = (const float*)d_in[11];
    const float* W2       = (const float*)d_in[12];
    const float* b2       = (const float*)d_in[13];
    float* out = (float*)d_out;

    const int n = in_sizes[2];       // 100000
    const int e = in_sizes[1] / 2;   // 600000
    const int* src = ei;
    const int* dst = ei + e;

    char* ws = (char*)d_ws;
    unsigned short* hWb = (unsigned short*)ws;                    // n*128 bf16
    unsigned short* hb  = hWb + (size_t)n * HD;                   // n*128 bf16
    float* a_s    = (float*)(hb + (size_t)n * HD);                // n
    float* a_d    = a_s + n;                                      // n
    float* alpha  = a_d + n;                                      // 128
    float* beta   = alpha + HD;                                   // 128
    float* pooled4= beta + HD;                                    // 4*GG*128
    float4* ps    = (float4*)(pooled4 + 4 * GG * HD);             // 256*32 f4
    float4* pq    = ps + 256 * 32;                                // 256*32 f4
    unsigned short* Wt = (unsigned short*)(pq + 256 * 32);        // 3*128*128
    int* counts   = (int*)(Wt + 3 * 16384);                       // n
    int* cursor   = counts + n;                                   // n
    int* offs     = cursor + n;                                   // n+1
    int* esrc     = offs + n + 1;                                 // e
    int* bsums    = esrc + e;                                     // 512
    int* boffs    = bsums + 512;                                  // 512

    const int nb = (n + 255) / 256;

    // ---- init (weights->bf16 transposed + zero counts/cursor), CSR build ----
    k_init<<<(2 * n + 255) / 256, 256, 0, stream>>>(Ws, Wt, counts, 2 * n);
    k_count<<<(e + 255) / 256, 256, 0, stream>>>(dst, counts, e);
    k_scan_reduce<<<nb, 256, 0, stream>>>(counts, bsums, n);
    k_scan_top<<<1, 512, 0, stream>>>(bsums, boffs, nb, offs, n);
    k_scan_apply<<<nb, 256, 0, stream>>>(counts, boffs, offs, n);
    k_scatter<<<(e + 255) / 256, 256, 0, stream>>>(src, dst, offs, cursor, esrc, e);

    // ---- GAT layers ----
    for (int l = 0; l < 3; ++l) {
        if (l == 0) {
            k_gemm_a32<<<(n + 127) / 128, 256, 0, stream>>>(
                x, Wt, att_src, att_dst, hWb, a_s, a_d, n);
        } else {
            k_gemm_a16<<<(n + 127) / 128, 256, 0, stream>>>(
                hb, Wt + l * 16384, att_src + l * HD, att_dst + l * HD,
                alpha, beta, hWb, a_s, a_d, n);
        }
        k_agg<<<(n + 3) / 4, 256, 0, stream>>>(hWb, offs, esrc, a_s, a_d,
                                               conv_bias + l * HD, hb, n);
        if (l < 2) {
            k_colstat2<<<256, 256, 0, stream>>>(hb, ps, pq, n);
            k_colfinish<<<1, 64, 0, stream>>>(ps, pq, gn_w + l * HD, gn_b + l * HD,
                                              gn_ms + l * HD, alpha, beta, 1.0f / n);
        }
    }

    // ---- pool + MLP ----
    k_pool<<<4 * GG, 256, 0, stream>>>(hb, batch, pooled4, n);
    k_mlp<<<GG, HD, 0, stream>>>(pooled4, W1, b1, W2, b2, out);
}

// Round 5
// 468.906 us; speedup vs baseline: 3.4482x; 1.0327x over previous
//
#include <hip/hip_runtime.h>
#include <math.h>

#define HD 128
#define GG 64

typedef __attribute__((ext_vector_type(8))) short short8;
typedef __attribute__((ext_vector_type(4))) float f32x4;

__device__ __forceinline__ float leaky(float x, float s) { return x > 0.f ? x : s * x; }

__device__ __forceinline__ unsigned short bf16_of(float f) {
    union { float f; unsigned u; } v; v.f = f;
    unsigned r = v.u + 0x7fffu + ((v.u >> 16) & 1u);
    return (unsigned short)(r >> 16);
}
__device__ __forceinline__ float f_of_bf16(unsigned short u) {
    union { unsigned u; float f; } v; v.u = ((unsigned)u) << 16;
    return v.f;
}

// ---------------- init: W->Wt bf16 transposed + zero counts/cursor ----------------
__global__ void k_init(const float* __restrict__ Ws, unsigned short* __restrict__ Wt,
                       int* __restrict__ counts2, int n2) {
    int i = blockIdx.x * 256 + threadIdx.x;
    if (i < 3 * 16384) {
        int l = i >> 14, rem = i & 16383;
        int nn = rem >> 7, k = rem & 127;
        Wt[i] = bf16_of(Ws[l * 16384 + k * 128 + nn]);
    }
    if (i < n2) counts2[i] = 0;
}

// ================= MFMA GEMM core =============
// Block: 128 rows x 128 cols, 256 threads (4 waves). LDS 64KB -> 2 blocks/CU.
// Epilogue: bf16 hW store + fused a_s/a_d row dots.

// ---- variant A: fp32 input (layer 0, no norm) ----
__global__ __launch_bounds__(256) void k_gemm_a32(
    const float* __restrict__ A, const unsigned short* __restrict__ Wt,
    const float* __restrict__ att_s, const float* __restrict__ att_d,
    unsigned short* __restrict__ hWb, float* __restrict__ a_s, float* __restrict__ a_d,
    int n) {
    __shared__ unsigned short As[128 * 128];
    __shared__ unsigned short Bs[128 * 128];
    const int tid = threadIdx.x;
    const int base = blockIdx.x * 128;

    const uint4* Wt4 = (const uint4*)Wt;
    uint4* Bs4 = (uint4*)Bs;
#pragma unroll
    for (int j = 0; j < 8; ++j) Bs4[tid + j * 256] = Wt4[tid + j * 256];

    const float4* A4 = (const float4*)A;
#pragma unroll
    for (int j = 0; j < 16; ++j) {
        int flat = tid + j * 256;           // 4096 float4 slots
        int r = flat >> 5, c4 = flat & 31;
        float4 v = make_float4(0.f, 0.f, 0.f, 0.f);
        if (base + r < n) v = A4[(size_t)(base + r) * 32 + c4];
        ushort4 b;
        b.x = bf16_of(v.x); b.y = bf16_of(v.y); b.z = bf16_of(v.z); b.w = bf16_of(v.w);
        *(ushort4*)&As[r * 128 + c4 * 4] = b;
    }
    __syncthreads();

    const int wave = tid >> 6, lane = tid & 63;
    const int m16 = lane & 15, quad = lane >> 4;
    f32x4 acc[2][8];
#pragma unroll
    for (int rt = 0; rt < 2; ++rt)
#pragma unroll
        for (int ct = 0; ct < 8; ++ct) acc[rt][ct] = (f32x4){0.f, 0.f, 0.f, 0.f};
#pragma unroll
    for (int kk = 0; kk < 4; ++kk) {
        short8 af[2];
#pragma unroll
        for (int rt = 0; rt < 2; ++rt)
            af[rt] = *(const short8*)&As[(wave * 32 + rt * 16 + m16) * 128 + kk * 32 + quad * 8];
#pragma unroll
        for (int ct = 0; ct < 8; ++ct) {
            short8 bfr = *(const short8*)&Bs[(ct * 16 + m16) * 128 + kk * 32 + quad * 8];
            acc[0][ct] = __builtin_amdgcn_mfma_f32_16x16x32_bf16(af[0], bfr, acc[0][ct], 0, 0, 0);
            acc[1][ct] = __builtin_amdgcn_mfma_f32_16x16x32_bf16(af[1], bfr, acc[1][ct], 0, 0, 0);
        }
    }
    __syncthreads();
#pragma unroll
    for (int rt = 0; rt < 2; ++rt) {
#pragma unroll
        for (int reg = 0; reg < 4; ++reg) {
            int lrow = wave * 32 + rt * 16 + quad * 4 + reg;
            float s = 0.f, dd = 0.f;
#pragma unroll
            for (int ct = 0; ct < 8; ++ct) {
                float v = acc[rt][ct][reg];
                int col = ct * 16 + m16;
                As[lrow * 128 + col] = bf16_of(v);
                s = fmaf(v, att_s[col], s);
                dd = fmaf(v, att_d[col], dd);
            }
#pragma unroll
            for (int off = 1; off < 16; off <<= 1) {
                s += __shfl_xor(s, off, 64);
                dd += __shfl_xor(dd, off, 64);
            }
            if (m16 == 0) {
                int gr = base + lrow;
                if (gr < n) { a_s[gr] = s; a_d[gr] = dd; }
            }
        }
    }
    __syncthreads();
    uint4* out4 = (uint4*)hWb;
    const uint4* AsC = (const uint4*)As;
#pragma unroll
    for (int j = 0; j < 8; ++j) {
        int flat = tid + j * 256;
        int r = flat >> 4;
        if (base + r < n) out4[(size_t)base * 16 + flat] = AsC[flat];
    }
}

// ---- variant B: bf16 input + GraphNorm affine + leaky (layers 1,2) ----
__global__ __launch_bounds__(256) void k_gemm_a16(
    const unsigned short* __restrict__ Ab, const unsigned short* __restrict__ Wt,
    const float* __restrict__ att_s, const float* __restrict__ att_d,
    const float* __restrict__ alpha, const float* __restrict__ beta,
    unsigned short* __restrict__ hWb, float* __restrict__ a_s, float* __restrict__ a_d,
    int n) {
    __shared__ unsigned short As[128 * 128];
    __shared__ unsigned short Bs[128 * 128];
    const int tid = threadIdx.x;
    const int base = blockIdx.x * 128;

    const uint4* Wt4 = (const uint4*)Wt;
    uint4* Bs4 = (uint4*)Bs;
#pragma unroll
    for (int j = 0; j < 8; ++j) Bs4[tid + j * 256] = Wt4[tid + j * 256];

    const uint4* A4 = (const uint4*)Ab;   // 8 bf16 per uint4
    const float4* al4 = (const float4*)alpha;
    const float4* be4 = (const float4*)beta;
#pragma unroll
    for (int j = 0; j < 8; ++j) {
        int flat = tid + j * 256;           // 2048 uint4 slots (128 rows x 16)
        int r = flat >> 4, c8 = flat & 15;
        uint4 raw = make_uint4(0u, 0u, 0u, 0u);
        if (base + r < n) raw = A4[(size_t)(base + r) * 16 + c8];
        float4 a0 = al4[c8 * 2], a1 = al4[c8 * 2 + 1];
        float4 b0 = be4[c8 * 2], b1 = be4[c8 * 2 + 1];
        float f0 = leaky(fmaf(f_of_bf16(raw.x & 0xffff), a0.x, b0.x), 0.01f);
        float f1 = leaky(fmaf(f_of_bf16(raw.x >> 16),    a0.y, b0.y), 0.01f);
        float f2 = leaky(fmaf(f_of_bf16(raw.y & 0xffff), a0.z, b0.z), 0.01f);
        float f3 = leaky(fmaf(f_of_bf16(raw.y >> 16),    a0.w, b0.w), 0.01f);
        float f4 = leaky(fmaf(f_of_bf16(raw.z & 0xffff), a1.x, b1.x), 0.01f);
        float f5 = leaky(fmaf(f_of_bf16(raw.z >> 16),    a1.y, b1.y), 0.01f);
        float f6 = leaky(fmaf(f_of_bf16(raw.w & 0xffff), a1.z, b1.z), 0.01f);
        float f7 = leaky(fmaf(f_of_bf16(raw.w >> 16),    a1.w, b1.w), 0.01f);
        uint4 pk;
        pk.x = (unsigned)bf16_of(f0) | ((unsigned)bf16_of(f1) << 16);
        pk.y = (unsigned)bf16_of(f2) | ((unsigned)bf16_of(f3) << 16);
        pk.z = (unsigned)bf16_of(f4) | ((unsigned)bf16_of(f5) << 16);
        pk.w = (unsigned)bf16_of(f6) | ((unsigned)bf16_of(f7) << 16);
        *(uint4*)&As[r * 128 + c8 * 8] = pk;
    }
    __syncthreads();

    const int wave = tid >> 6, lane = tid & 63;
    const int m16 = lane & 15, quad = lane >> 4;
    f32x4 acc[2][8];
#pragma unroll
    for (int rt = 0; rt < 2; ++rt)
#pragma unroll
        for (int ct = 0; ct < 8; ++ct) acc[rt][ct] = (f32x4){0.f, 0.f, 0.f, 0.f};
#pragma unroll
    for (int kk = 0; kk < 4; ++kk) {
        short8 af[2];
#pragma unroll
        for (int rt = 0; rt < 2; ++rt)
            af[rt] = *(const short8*)&As[(wave * 32 + rt * 16 + m16) * 128 + kk * 32 + quad * 8];
#pragma unroll
        for (int ct = 0; ct < 8; ++ct) {
            short8 bfr = *(const short8*)&Bs[(ct * 16 + m16) * 128 + kk * 32 + quad * 8];
            acc[0][ct] = __builtin_amdgcn_mfma_f32_16x16x32_bf16(af[0], bfr, acc[0][ct], 0, 0, 0);
            acc[1][ct] = __builtin_amdgcn_mfma_f32_16x16x32_bf16(af[1], bfr, acc[1][ct], 0, 0, 0);
        }
    }
    __syncthreads();
#pragma unroll
    for (int rt = 0; rt < 2; ++rt) {
#pragma unroll
        for (int reg = 0; reg < 4; ++reg) {
            int lrow = wave * 32 + rt * 16 + quad * 4 + reg;
            float s = 0.f, dd = 0.f;
#pragma unroll
            for (int ct = 0; ct < 8; ++ct) {
                float v = acc[rt][ct][reg];
                int col = ct * 16 + m16;
                As[lrow * 128 + col] = bf16_of(v);
                s = fmaf(v, att_s[col], s);
                dd = fmaf(v, att_d[col], dd);
            }
#pragma unroll
            for (int off = 1; off < 16; off <<= 1) {
                s += __shfl_xor(s, off, 64);
                dd += __shfl_xor(dd, off, 64);
            }
            if (m16 == 0) {
                int gr = base + lrow;
                if (gr < n) { a_s[gr] = s; a_d[gr] = dd; }
            }
        }
    }
    __syncthreads();
    uint4* out4 = (uint4*)hWb;
    const uint4* AsC = (const uint4*)As;
#pragma unroll
    for (int j = 0; j < 8; ++j) {
        int flat = tid + j * 256;
        int r = flat >> 4;
        if (base + r < n) out4[(size_t)base * 16 + flat] = AsC[flat];
    }
}

// ---------------- CSR build ----------------
__global__ void k_count(const int* __restrict__ dst, int* __restrict__ counts, int e) {
    int i = blockIdx.x * blockDim.x + threadIdx.x;
    if (i < e) atomicAdd(&counts[dst[i]], 1);
}

__global__ void k_scan_reduce(const int* __restrict__ counts, int* __restrict__ bsums, int n) {
    __shared__ int s[256];
    int tid = threadIdx.x;
    int i = blockIdx.x * 256 + tid;
    s[tid] = (i < n) ? counts[i] : 0;
    __syncthreads();
#pragma unroll
    for (int off = 128; off; off >>= 1) {
        if (tid < off) s[tid] += s[tid + off];
        __syncthreads();
    }
    if (tid == 0) bsums[blockIdx.x] = s[0];
}

__global__ void k_scan_top(const int* __restrict__ bsums, int* __restrict__ boffs,
                           int nb, int* __restrict__ offs, int n_nodes) {
    __shared__ int s[512];
    int tid = threadIdx.x;
    int own = (tid < nb) ? bsums[tid] : 0;
    s[tid] = own;
    __syncthreads();
    for (int off = 1; off < 512; off <<= 1) {
        int t = 0;
        if (tid >= off) t = s[tid - off];
        __syncthreads();
        s[tid] += t;
        __syncthreads();
    }
    if (tid < nb) boffs[tid] = s[tid] - own;
    if (tid == 511) offs[n_nodes] = s[511];
}

__global__ void k_scan_apply(const int* __restrict__ counts, const int* __restrict__ boffs,
                             int* __restrict__ offs, int n) {
    __shared__ int s[256];
    int tid = threadIdx.x;
    int i = blockIdx.x * 256 + tid;
    int own = (i < n) ? counts[i] : 0;
    s[tid] = own;
    __syncthreads();
    for (int off = 1; off < 256; off <<= 1) {
        int t = 0;
        if (tid >= off) t = s[tid - off];
        __syncthreads();
        s[tid] += t;
        __syncthreads();
    }
    if (i < n) offs[i] = boffs[blockIdx.x] + s[tid] - own;
}

__global__ void k_scatter(const int* __restrict__ src, const int* __restrict__ dst,
                          const int* __restrict__ offs, int* __restrict__ cursor,
                          int* __restrict__ esrc, int e) {
    int i = blockIdx.x * blockDim.x + threadIdx.x;
    if (i < e) {
        int d = dst[i];
        int pos = offs[d] + atomicAdd(&cursor[d], 1);
        esrc[pos] = src[i];
    }
}

// ---------------- fused attention softmax + aggregation -> bf16 h ----------------
// One 64-lane wave per dst node. Four 16-lane groups each gather a FULL 256B row
// (uint4 = 16B/lane) for edges p, p+1, p+2, p+3 -> 4 row-gathers in flight/wave.
// Cross-group merge via shfl_xor 16/32 once per dst.
__global__ __launch_bounds__(256) void k_agg(const unsigned short* __restrict__ hWb,
                                             const int* __restrict__ offs,
                                             const int* __restrict__ esrc,
                                             const float* __restrict__ a_s,
                                             const float* __restrict__ a_d,
                                             const float* __restrict__ bias,
                                             unsigned short* __restrict__ hb, int n) {
    int d = blockIdx.x * 4 + (threadIdx.x >> 6);
    int lane = threadIdx.x & 63;
    int q = lane >> 4;        // edge-slot group 0..3
    int l16 = lane & 15;      // 16B chunk within row (features l16*8 .. l16*8+7)
    if (d >= n) return;
    int p0 = offs[d], p1 = offs[d + 1];
    float ad = a_d[d];
    const uint4* hW8 = (const uint4*)hWb;   // 16 uint4 per 128-col row
    float acc[8] = {0.f, 0.f, 0.f, 0.f, 0.f, 0.f, 0.f, 0.f};
    float ssum = 0.f;
    int s_cur = (p0 + q < p1) ? esrc[p0 + q] : 0;
    for (int p = p0 + q; p < p1; p += 4) {
        int s = s_cur;
        if (p + 4 < p1) s_cur = esrc[p + 4];
        float e = leaky(a_s[s] + ad, 0.2f);
        float ex = __expf(e);
        ssum += ex;
        uint4 raw = hW8[(size_t)s * 16 + l16];
        acc[0] = fmaf(ex, f_of_bf16(raw.x & 0xffff), acc[0]);
        acc[1] = fmaf(ex, f_of_bf16(raw.x >> 16),    acc[1]);
        acc[2] = fmaf(ex, f_of_bf16(raw.y & 0xffff), acc[2]);
        acc[3] = fmaf(ex, f_of_bf16(raw.y >> 16),    acc[3]);
        acc[4] = fmaf(ex, f_of_bf16(raw.z & 0xffff), acc[4]);
        acc[5] = fmaf(ex, f_of_bf16(raw.z >> 16),    acc[5]);
        acc[6] = fmaf(ex, f_of_bf16(raw.w & 0xffff), acc[6]);
        acc[7] = fmaf(ex, f_of_bf16(raw.w >> 16),    acc[7]);
    }
    // merge the 4 edge-slot groups (lanes with equal l16 hold the same features)
    ssum += __shfl_xor(ssum, 16, 64);
    ssum += __shfl_xor(ssum, 32, 64);
#pragma unroll
    for (int k = 0; k < 8; ++k) {
        acc[k] += __shfl_xor(acc[k], 16, 64);
        acc[k] += __shfl_xor(acc[k], 32, 64);
    }
    if (lane < 16) {
        float inv = 1.f / (ssum + 1e-16f);
        const float4* b4p = (const float4*)bias;
        float4 bb0 = b4p[l16 * 2], bb1 = b4p[l16 * 2 + 1];
        uint4 o;
        o.x = (unsigned)bf16_of(fmaf(acc[0], inv, bb0.x)) |
              ((unsigned)bf16_of(fmaf(acc[1], inv, bb0.y)) << 16);
        o.y = (unsigned)bf16_of(fmaf(acc[2], inv, bb0.z)) |
              ((unsigned)bf16_of(fmaf(acc[3], inv, bb0.w)) << 16);
        o.z = (unsigned)bf16_of(fmaf(acc[4], inv, bb1.x)) |
              ((unsigned)bf16_of(fmaf(acc[5], inv, bb1.y)) << 16);
        o.w = (unsigned)bf16_of(fmaf(acc[6], inv, bb1.z)) |
              ((unsigned)bf16_of(fmaf(acc[7], inv, bb1.w)) << 16);
        ((uint4*)hb)[(size_t)d * 16 + l16] = o;
    }
}

// ---------------- GraphNorm stats stage A (bf16 input) ----------------
__global__ __launch_bounds__(256) void k_colstat2(const unsigned short* __restrict__ hb,
                                                  float4* __restrict__ ps,
                                                  float4* __restrict__ pq, int n) {
    const ushort4* h4 = (const ushort4*)hb;
    const int tid = threadIdx.x;
    const int total = n * 32;
    float4 s = make_float4(0.f, 0.f, 0.f, 0.f);
    float4 q = make_float4(0.f, 0.f, 0.f, 0.f);
    for (int i = blockIdx.x * 256 + tid; i < total; i += 256 * 256) {
        ushort4 hv = h4[i];   // (i & 31) == (tid & 31): fixed column group
        float vx = f_of_bf16(hv.x), vy = f_of_bf16(hv.y);
        float vz = f_of_bf16(hv.z), vw = f_of_bf16(hv.w);
        s.x += vx; s.y += vy; s.z += vz; s.w += vw;
        q.x = fmaf(vx, vx, q.x);
        q.y = fmaf(vy, vy, q.y);
        q.z = fmaf(vz, vz, q.z);
        q.w = fmaf(vw, vw, q.w);
    }
    __shared__ float4 ss[256];
    __shared__ float4 sq[256];
    ss[tid] = s; sq[tid] = q;
    __syncthreads();
    if (tid < 32) {
        float4 S = ss[tid], Q = sq[tid];
#pragma unroll
        for (int k = 1; k < 8; ++k) {
            float4 a = ss[tid + 32 * k];
            float4 b = sq[tid + 32 * k];
            S.x += a.x; S.y += a.y; S.z += a.z; S.w += a.w;
            Q.x += b.x; Q.y += b.y; Q.z += b.z; Q.w += b.w;
        }
        ps[blockIdx.x * 32 + tid] = S;
        pq[blockIdx.x * 32 + tid] = Q;
    }
}

// ---------------- stage B: reduce partials + alpha/beta ----------------
__global__ void k_colfinish(const float4* __restrict__ ps, const float4* __restrict__ pq,
                            const float* __restrict__ w, const float* __restrict__ bb,
                            const float* __restrict__ ms, float* __restrict__ alpha,
                            float* __restrict__ beta, float inv_n) {
    int t = threadIdx.x;
    if (t >= 32) return;
    float4 S = make_float4(0.f, 0.f, 0.f, 0.f);
    float4 Q = make_float4(0.f, 0.f, 0.f, 0.f);
    for (int b = 0; b < 256; ++b) {
        float4 a = ps[b * 32 + t];
        float4 c = pq[b * 32 + t];
        S.x += a.x; S.y += a.y; S.z += a.z; S.w += a.w;
        Q.x += c.x; Q.y += c.y; Q.z += c.z; Q.w += c.w;
    }
    float sv[4] = {S.x, S.y, S.z, S.w};
    float qv[4] = {Q.x, Q.y, Q.z, Q.w};
#pragma unroll
    for (int k = 0; k < 4; ++k) {
        int c = t * 4 + k;
        float mean = sv[k] * inv_n;
        float ex2 = qv[k] * inv_n;
        float m2 = mean * ms[c];
        float var = ex2 - 2.f * m2 * mean + m2 * m2;
        float a = w[c] * rsqrtf(var + 1e-5f);
        alpha[c] = a;
        beta[c] = bb[c] - m2 * a;
    }
}

// ---------------- global_add_pool: 4 blocks/graph, binary search, no atomics ----------------
__device__ __forceinline__ int lower_bound_i(const int* __restrict__ a, int n, int key) {
    int lo = 0, hi = n;
    while (lo < hi) {
        int mid = (lo + hi) >> 1;
        if (a[mid] < key) lo = mid + 1; else hi = mid;
    }
    return lo;
}

__global__ __launch_bounds__(256) void k_pool(const unsigned short* __restrict__ hb,
                                              const int* __restrict__ batch,
                                              float* __restrict__ pooled4, int n) {
    int g = blockIdx.x >> 2, t4 = blockIdx.x & 3;
    int lo = lower_bound_i(batch, n, g);
    int hi = lower_bound_i(batch, n, g + 1);
    int len = hi - lo;
    int q = (len + 3) >> 2;
    int r0 = lo + t4 * q;
    int r1 = min(r0 + q, hi);
    int c4 = threadIdx.x & 31, rg = threadIdx.x >> 5;
    const ushort4* h4 = (const ushort4*)hb;
    float4 acc = make_float4(0.f, 0.f, 0.f, 0.f);
    for (int r = r0 + rg; r < r1; r += 8) {
        ushort4 hv = h4[(size_t)r * 32 + c4];
        acc.x += f_of_bf16(hv.x);
        acc.y += f_of_bf16(hv.y);
        acc.z += f_of_bf16(hv.z);
        acc.w += f_of_bf16(hv.w);
    }
    __shared__ float4 sred[256];
    sred[threadIdx.x] = acc;
    __syncthreads();
    if (threadIdx.x < 32) {
        float4 S = sred[threadIdx.x];
#pragma unroll
        for (int k = 1; k < 8; ++k) {
            float4 a = sred[threadIdx.x + 32 * k];
            S.x += a.x; S.y += a.y; S.z += a.z; S.w += a.w;
        }
        ((float4*)pooled4)[(t4 * GG + g) * 32 + threadIdx.x] = S;
    }
}

// ---------------- final MLP (sums the 4 pool partials) ----------------
__global__ __launch_bounds__(128) void k_mlp(const float* __restrict__ pooled4,
                                             const float* __restrict__ W1,
                                             const float* __restrict__ b1,
                                             const float* __restrict__ W2,
                                             const float* __restrict__ b2,
                                             float* __restrict__ out) {
    __shared__ float pr[HD];
    __shared__ float zs[HD];
    int g = blockIdx.x, t = threadIdx.x;
    float pv = 0.f;
#pragma unroll
    for (int k = 0; k < 4; ++k) pv += pooled4[(k * GG + g) * HD + t];
    pr[t] = pv;
    __syncthreads();
    float acc = b1[t];
#pragma unroll 8
    for (int k = 0; k < HD; ++k) acc = fmaf(pr[k], W1[k * HD + t], acc);
    zs[t] = leaky(acc, 0.01f);
    __syncthreads();
    if (t < 64) {
        float a2 = b2[t];
#pragma unroll 8
        for (int k = 0; k < HD; ++k) a2 = fmaf(zs[k], W2[k * 64 + t], a2);
        out[g * 64 + t] = a2;
    }
}

extern "C" void kernel_launch(void* const* d_in, const int* in_sizes, int n_in,
                              void* d_out, int out_size, void* d_ws, size_t ws_size,
                              hipStream_t stream) {
    const float* x        = (const float*)d_in[0];
    const int*   ei       = (const int*)d_in[1];
    const int*   batch    = (const int*)d_in[2];
    const float* Ws       = (const float*)d_in[3];
    const float* att_src  = (const float*)d_in[4];
    const float* att_dst  = (const float*)d_in[5];
    const float* conv_bias= (const float*)d_in[6];
    const float* gn_w     = (const float*)d_in[7];
    const float* gn_b     = (const float*)d_in[8];
    const float* gn_ms    = (const float*)d_in[9];
    const float* W1       = (const float*)d_in[10];
    const float* b1       = (const float*)d_in[11];
    const float* W2       = (const float*)d_in[12];
    const float* b2       = (const float*)d_in[13];
    float* out = (float*)d_out;

    const int n = in_sizes[2];       // 100000
    const int e = in_sizes[1] / 2;   // 600000
    const int* src = ei;
    const int* dst = ei + e;

    char* ws = (char*)d_ws;
    unsigned short* hWb = (unsigned short*)ws;                    // n*128 bf16
    unsigned short* hb  = hWb + (size_t)n * HD;                   // n*128 bf16
    float* a_s    = (float*)(hb + (size_t)n * HD);                // n
    float* a_d    = a_s + n;                                      // n
    float* alpha  = a_d + n;                                      // 128
    float* beta   = alpha + HD;                                   // 128
    float* pooled4= beta + HD;                                    // 4*GG*128
    float4* ps    = (float4*)(pooled4 + 4 * GG * HD);             // 256*32 f4
    float4* pq    = ps + 256 * 32;                                // 256*32 f4
    unsigned short* Wt = (unsigned short*)(pq + 256 * 32);        // 3*128*128
    int* counts   = (int*)(Wt + 3 * 16384);                       // n
    int* cursor   = counts + n;                                   // n
    int* offs     = cursor + n;                                   // n+1
    int* esrc     = offs + n + 1;                                 // e
    int* bsums    = esrc + e;                                     // 512
    int* boffs    = bsums + 512;                                  // 512

    const int nb = (n + 255) / 256;

    // ---- init (weights->bf16 transposed + zero counts/cursor), CSR build ----
    k_init<<<(2 * n + 255) / 256, 256, 0, stream>>>(Ws, Wt, counts, 2 * n);
    k_count<<<(e + 255) / 256, 256, 0, stream>>>(dst, counts, e);
    k_scan_reduce<<<nb, 256, 0, stream>>>(counts, bsums, n);
    k_scan_top<<<1, 512, 0, stream>>>(bsums, boffs, nb, offs, n);
    k_scan_apply<<<nb, 256, 0, stream>>>(counts, boffs, offs, n);
    k_scatter<<<(e + 255) / 256, 256, 0, stream>>>(src, dst, offs, cursor, esrc, e);

    // ---- GAT layers ----
    for (int l = 0; l < 3; ++l) {
        if (l == 0) {
            k_gemm_a32<<<(n + 127) / 128, 256, 0, stream>>>(
                x, Wt, att_src, att_dst, hWb, a_s, a_d, n);
        } else {
            k_gemm_a16<<<(n + 127) / 128, 256, 0, stream>>>(
                hb, Wt + l * 16384, att_src + l * HD, att_dst + l * HD,
                alpha, beta, hWb, a_s, a_d, n);
        }
        k_agg<<<(n + 3) / 4, 256, 0, stream>>>(hWb, offs, esrc, a_s, a_d,
                                               conv_bias + l * HD, hb, n);
        if (l < 2) {
            k_colstat2<<<256, 256, 0, stream>>>(hb, ps, pq, n);
            k_colfinish<<<1, 64, 0, stream>>>(ps, pq, gn_w + l * HD, gn_b + l * HD,
                                              gn_ms + l * HD, alpha, beta, 1.0f / n);
        }
    }

    // ---- pool + MLP ----
    k_pool<<<4 * GG, 256, 0, stream>>>(hb, batch, pooled4, n);
    k_mlp<<<GG, HD, 0, stream>>>(pooled4, W1, b1, W2, b2, out);
}